// Round 6
// baseline (1079.350 us; speedup 1.0000x reference)
//
#include <hip/hip_runtime.h>
#include <cstddef>
#include <cstdint>

#define N_NODES 50000
#define N_EDGES 800000
#define F_IN 50
#define K1PAD 64
#define H_DIM 512
#define O_DIM 121
#define N_GROUPS 20
#define EPSV 1e-5f
#define M_PAD 50176   // 392 * 128
#define M_TILES 392

#define SCAN_BLK 256
#define SCAN_NBLK ((N_NODES + SCAN_BLK - 1) / SCAN_BLK)  // 196
#define WALL_EL 1769472
#define XB_EL (M_PAD * K1PAD)

typedef unsigned short u16;
typedef __attribute__((ext_vector_type(8))) short short8;          // 8 bf16 (4 VGPRs)
typedef __attribute__((ext_vector_type(8))) unsigned short u16x8;  // 16B vector load
typedef __attribute__((ext_vector_type(4))) float f32x4;

__device__ __forceinline__ float b2f(u16 u) {
  union { unsigned int i; float f; } v; v.i = ((unsigned int)u) << 16; return v.f;
}
__device__ __forceinline__ u16 f2b(float f) {
  union { float f; unsigned int i; } v; v.f = f;
  unsigned int x = v.i;
  return (u16)((x + 0x7fffu + ((x >> 16) & 1u)) >> 16);  // RNE
}

__device__ __forceinline__ void gl_lds16(const void* g, void* l) {
  __builtin_amdgcn_global_load_lds(
      (__attribute__((address_space(1))) void*)(g),
      (__attribute__((address_space(3))) void*)(l), 16, 0, 0);
}

// ---------------- graph preprocessing ----------------

__global__ void k_deg(const int* __restrict__ dst, int* __restrict__ deg) {
  int e = blockIdx.x * blockDim.x + threadIdx.x;
  if (e < N_EDGES) atomicAdd(&deg[dst[e]], 1);
}

__global__ void k_scan1(const int* __restrict__ deg, int* __restrict__ off,
                        int* __restrict__ bsum) {
  __shared__ int buf[SCAN_BLK];
  int gid = blockIdx.x * SCAN_BLK + threadIdx.x;
  buf[threadIdx.x] = (gid < N_NODES) ? deg[gid] : 0;
  __syncthreads();
  for (int d = 1; d < SCAN_BLK; d <<= 1) {
    int t = (threadIdx.x >= d) ? buf[threadIdx.x - d] : 0;
    __syncthreads();
    buf[threadIdx.x] += t;
    __syncthreads();
  }
  if (gid < N_NODES) off[gid + 1] = buf[threadIdx.x];
  if (threadIdx.x == SCAN_BLK - 1) bsum[blockIdx.x] = buf[threadIdx.x];
}

// block 0: scan of block sums; block 1: group bounds from sorted batch
__global__ void k_scan2_gbounds(int* __restrict__ bsum, const int* __restrict__ batch,
                                int* __restrict__ gstart, float* __restrict__ inv_sz) {
  int t = threadIdx.x;
  if (blockIdx.x == 0) {
    __shared__ int buf[256];
    buf[t] = (t < SCAN_NBLK) ? bsum[t] : 0;
    __syncthreads();
    for (int d = 1; d < 256; d <<= 1) {
      int v = (t >= d) ? buf[t - d] : 0;
      __syncthreads();
      buf[t] += v;
      __syncthreads();
    }
    if (t < SCAN_NBLK) bsum[t] = buf[t];
  } else {
    if (t <= N_GROUPS) {
      int lo = 0, hi = N_NODES;
      while (lo < hi) {
        int mid = (lo + hi) >> 1;
        if (batch[mid] < t) lo = mid + 1; else hi = mid;
      }
      gstart[t] = lo;
    }
    __syncthreads();
    if (t < N_GROUPS) {
      int sz = gstart[t + 1] - gstart[t];
      inv_sz[t] = 1.0f / (float)max(sz, 1);
    }
  }
}

__global__ void k_scan3prep(int* __restrict__ off, const int* __restrict__ bsum,
                            const int* __restrict__ deg, float* __restrict__ inv_deg,
                            int* __restrict__ cursor) {
  int gid = blockIdx.x * SCAN_BLK + threadIdx.x;
  if (gid < N_NODES) {
    int add = (blockIdx.x > 0) ? bsum[blockIdx.x - 1] : 0;
    int v = off[gid + 1] + add;
    off[gid + 1] = v;
    if (gid + 1 < N_NODES) cursor[gid + 1] = v;
    inv_deg[gid] = 1.0f / (float)max(deg[gid], 1);
  }
  if (gid == 0) { off[0] = 0; cursor[0] = 0; }
}

__global__ void k_scatter(const int* __restrict__ src, const int* __restrict__ dst,
                          int* __restrict__ cursor, int* __restrict__ csr_src) {
  int e = blockIdx.x * blockDim.x + threadIdx.x;
  if (e < N_EDGES) {
    int p = atomicAdd(&cursor[dst[e]], 1);
    csr_src[p] = src[e];
  }
}

// WINDOW-LOCAL degree sort (counting sort per 196-node chunk). Gives the
// sliced gather's waves uniform trip counts WITHOUT destroying CSR cache
// locality (r3 lesson: global degree sort randomized CSR windows -> L2
// thrash). All reads/writes stay inside the ~13KB per-window footprint.
__global__ __launch_bounds__(256) void k_wsort(const int* __restrict__ deg,
                                               int* __restrict__ perm) {
  __shared__ int hist[256];
  __shared__ int scanb[256];
  __shared__ int cur[256];
  const int per = (N_NODES + 255) / 256;  // 196, matches agg chunking
  int b0 = blockIdx.x * per;
  int cnt = min(per, N_NODES - b0);
  int t = threadIdx.x;
  hist[t] = 0;
  __syncthreads();
  int d = 0;
  if (t < cnt) {
    d = min(deg[b0 + t], 255);
    atomicAdd(&hist[d], 1);
  }
  __syncthreads();
  int v = hist[t];
  scanb[t] = v;
  __syncthreads();
  for (int s = 1; s < 256; s <<= 1) {
    int u = (t >= s) ? scanb[t - s] : 0;
    __syncthreads();
    scanb[t] += u;
    __syncthreads();
  }
  cur[t] = scanb[t] - v;  // exclusive
  __syncthreads();
  if (t < cnt) {
    int p = atomicAdd(&cur[d], 1);
    perm[b0 + p] = b0 + t;
  }
}

// ---------------- conversions (x pad + all weights, one launch) -------------
struct WcSrc { const float* p[10]; };
__global__ void k_convert_all(const float* __restrict__ x, WcSrc s,
                              u16* __restrict__ xb, u16* __restrict__ wall) {
  int idx = blockIdx.x * blockDim.x + threadIdx.x;
  if (idx < XB_EL) {
    int r = idx >> 6, c = idx & (K1PAD - 1);
    float v = (r < N_NODES && c < F_IN) ? x[r * F_IN + c] : 0.f;
    xb[idx] = f2b(v);
    return;
  }
  idx -= XB_EL;
  if (idx >= WALL_EL) return;
  const int seg_start[10] = {0, 32768, 65536, 327680, 589824, 851968,
                             1114112, 1376256, 1638400, 1703936};
  const int jr[10]  = {512, 512, 512, 512, 512, 512, 512, 512, 121, 121};
  const int kin[10] = {50, 50, 512, 512, 512, 512, 512, 512, 512, 512};
  const int ksh[10] = {6, 6, 9, 9, 9, 9, 9, 9, 9, 9};
  int sgi = 0;
#pragma unroll
  for (int t = 1; t < 10; ++t)
    if (idx >= seg_start[t]) sgi = t;
  int local = idx - seg_start[sgi];
  int j = local >> ksh[sgi];
  int k = local & ((1 << ksh[sgi]) - 1);
  float v = (j < jr[sgi] && k < kin[sgi]) ? s.p[sgi][j * kin[sgi] + k] : 0.f;
  wall[idx] = f2b(v);
}

// ---------------- aggregation ----------------

__global__ void k_agg_small(const u16* __restrict__ xb, const int* __restrict__ off,
                            const int* __restrict__ srcs, const float* __restrict__ inv_deg,
                            u16* __restrict__ agg) {
  int n = blockIdx.x;
  int f = threadIdx.x;  // 0..63
  int b = off[n], e = off[n + 1];
  float s = 0.f;
  for (int i = b; i < e; ++i) s += b2f(xb[(size_t)srcs[i] * K1PAD + f]);
  agg[(size_t)n * K1PAD + f] = f2b(s * inv_deg[n]);
}

// layers 2..4 aggregation, XCD-sliced. h stored SLICED: 16 regions of
// [M_PAD][32] u16 (3.2MB each); slice s = xcd*2+ph processed only by blocks
// on XCD s>>1 (blockIdx&7 -> XCD round-robin).
// ONE PHASE PER DISPATCH (r4 lesson: both phases resident -> 2 slices + CSR
// > 4MB L2 -> thrash). Nodes walked in WINDOW-SORTED order (k_wsort): waves'
// 16 node-groups get near-uniform degrees (kills the max-of-Poisson 1.7x
// divergence waste) while all CSR traffic stays in the per-window ~13KB.
#define AGG_BLKS 2048  // 256 chunks x 8 XCDs
__global__ __launch_bounds__(256) void k_agg_slice(
    const u16* __restrict__ hs, const int* __restrict__ off,
    const int* __restrict__ srcs, const float* __restrict__ inv_deg,
    const int* __restrict__ perm, u16* __restrict__ aggs, int ph) {
  const int xcd = blockIdx.x & 7;
  const int chunk = blockIdx.x >> 3;                 // 0..255
  const int nchunk = AGG_BLKS / 8;                   // 256
  const int per = (N_NODES + nchunk - 1) / nchunk;   // 196
  const int p0 = chunk * per;
  const int p1 = min(p0 + per, N_NODES);
  const int grp = threadIdx.x >> 2;       // 0..63 node-groups per block
  const int sub = (threadIdx.x & 3) * 8;  // u16 offset of this lane's 16B
  const int s = xcd * 2 + ph;
  const u16* hsl = hs + (size_t)s * M_PAD * 32 + sub;
  u16* asl = aggs + (size_t)s * M_PAD * 32 + sub;
  for (int p = p0 + grp; p < p1; p += 64) {
    int n = perm[p];
    int b = off[n], e = off[n + 1];
    float a[8] = {};
    int i = b;
    for (; i + 4 <= e; i += 4) {
      u16x8 v0 = *(const u16x8*)(hsl + (size_t)srcs[i + 0] * 32);
      u16x8 v1 = *(const u16x8*)(hsl + (size_t)srcs[i + 1] * 32);
      u16x8 v2 = *(const u16x8*)(hsl + (size_t)srcs[i + 2] * 32);
      u16x8 v3 = *(const u16x8*)(hsl + (size_t)srcs[i + 3] * 32);
#pragma unroll
      for (int j = 0; j < 8; ++j)
        a[j] += (b2f(v0[j]) + b2f(v1[j])) + (b2f(v2[j]) + b2f(v3[j]));
    }
    for (; i < e; ++i) {
      u16x8 v0 = *(const u16x8*)(hsl + (size_t)srcs[i] * 32);
#pragma unroll
      for (int j = 0; j < 8; ++j) a[j] += b2f(v0[j]);
    }
    float w = inv_deg[n];
    u16x8 r;
#pragma unroll
    for (int j = 0; j < 8; ++j) r[j] = f2b(a[j] * w);
    *(u16x8*)(asl + (size_t)n * 32) = r;
  }
}

// layer 5 final: out[n] = inv_deg[n]*sum(Pl[src]) + Pr[n] + bias (121 cols)
__global__ __launch_bounds__(256) void k_agg_final(
    const u16* __restrict__ Plb, const float* __restrict__ Prf,
    const int* __restrict__ off, const int* __restrict__ srcs,
    const float* __restrict__ inv_deg, const float* __restrict__ bias,
    float* __restrict__ out) {
  int n = blockIdx.x * 8 + (threadIdx.x >> 5);
  if (n >= N_NODES) return;
  int l = threadIdx.x & 31;
  int c0 = l * 4;
  int b = off[n], e = off[n + 1];
  float a0 = 0.f, a1 = 0.f, a2 = 0.f, a3 = 0.f;
  int i = b;
  for (; i + 2 <= e; i += 2) {
    ushort4 v0 = ((const ushort4*)(Plb + (size_t)srcs[i] * 128))[l];
    ushort4 v1 = ((const ushort4*)(Plb + (size_t)srcs[i + 1] * 128))[l];
    a0 += b2f(v0.x) + b2f(v1.x); a1 += b2f(v0.y) + b2f(v1.y);
    a2 += b2f(v0.z) + b2f(v1.z); a3 += b2f(v0.w) + b2f(v1.w);
  }
  if (i < e) {
    ushort4 v0 = ((const ushort4*)(Plb + (size_t)srcs[i] * 128))[l];
    a0 += b2f(v0.x); a1 += b2f(v0.y); a2 += b2f(v0.z); a3 += b2f(v0.w);
  }
  float w = inv_deg[n];
  float4 pr = ((const float4*)(Prf + (size_t)n * 128))[l];
  float r0 = a0 * w + pr.x, r1 = a1 * w + pr.y;
  float r2 = a2 * w + pr.z, r3 = a3 * w + pr.w;
  size_t ob = (size_t)n * O_DIM;
  if (c0 + 0 < O_DIM) out[ob + c0 + 0] = r0 + bias[c0 + 0];
  if (c0 + 1 < O_DIM) out[ob + c0 + 1] = r1 + bias[c0 + 1];
  if (c0 + 2 < O_DIM) out[ob + c0 + 2] = r2 + bias[c0 + 2];
  if (c0 + 3 < O_DIM) out[ob + c0 + 3] = r3 + bias[c0 + 3];
}

// ---------------- MFMA GEMM ----------------
// DUAL(OUTMODE 0): C = A*Wl^T + X*Wr^T + b, bf16 out [*, 512]; GraphNorm
//   stats fused in epilogue. !DUAL(OUTMODE 1): P = A*Wl^T split bf16/f32.
// SL: A/X in the 16x[M_PAD][32] sliced layout; staging chunks stay
//   16B-contiguous, so only base/stride constants change.
// PIPELINE (r5 fix for the 62%-idle latency stall): A/X (slow: L3/HBM)
//   double-buffered and prefetched one K-step ahead; Wl/Wr (L2-hot)
//   single-buffered. Counted s_waitcnt vmcnt(4/2) drains only A/X(t)+W(t),
//   leaving A/X(t+1) in flight ACROSS the barrier (T4). Raw s_barrier +
//   explicit lgkmcnt(0)+sched_barrier(0) before the bottom barrier (rule 18)
//   so frag ds_reads complete before the next W-stage overwrites Ls/Rs.
//   Queue algebra per wave at vmcnt: [A/X(t):4|2][W(t):4|2][A/X(t+1):4|2];
//   vmcnt(4|2) completes the first two groups exactly. Last iter: vmcnt(0).

#define TM 128
#define TK 32

template <int JB, bool DUAL, int OUTMODE, bool SL>
__global__ __launch_bounds__(256, 4) void k_gemm_mfma(
    const u16* __restrict__ A, const u16* __restrict__ X,
    const u16* __restrict__ Wl, const u16* __restrict__ Wr,
    const float* __restrict__ bias, void* __restrict__ C0,
    void* __restrict__ C1, const int* __restrict__ batch,
    float* __restrict__ ssum, float* __restrict__ ssq, int K) {
  __shared__ u16 As[2][TM * TK];
  __shared__ u16 Ls[TM * TK];
  __shared__ u16 Xs[DUAL ? 2 * TM * TK : 1];
  __shared__ u16 Rs[DUAL ? TM * TK : 1];

  int id = blockIdx.x;
  const int nfull = (M_TILES >> 3) * 8 * JB;
  int m_t, j_t;
  if (id < nfull) {
    m_t = (id / (8 * JB)) * 8 + (id & 7);
    j_t = (id >> 3) & (JB - 1);
  } else {
    int rem = id - nfull;
    const int nrem = (M_TILES & 7) ? (M_TILES & 7) : 1;
    m_t = (M_TILES & ~7) + rem % nrem;
    j_t = rem / nrem;
  }
  int m0 = m_t * TM;
  int j0 = j_t * 128;

  int tid = threadIdx.x;
  int lane = tid & 63;
  int wave = tid >> 6;
  int quad = lane >> 4;
  int lr = lane & 15;
  int wm = (wave & 1) * 64;
  int wn = (wave >> 1) * 64;

  f32x4 acc[4][4] = {};

  int sr = tid >> 2;
  int sc = (tid & 3) * 8;
  const size_t kstep = SL ? (size_t)M_PAD * 32 : (size_t)TK;
  const size_t rstep = SL ? (size_t)64 * 32 : (size_t)64 * K;
  const u16* Ap = A + (SL ? (size_t)(m0 + sr) * 32 + sc
                          : (size_t)(m0 + sr) * K + sc);
  const u16* Xp = nullptr;
  if constexpr (DUAL)
    Xp = X + (SL ? (size_t)(m0 + sr) * 32 + sc
                 : (size_t)(m0 + sr) * K + sc);
  size_t joff0 = (size_t)(j0 + sr) * K + sc;
  size_t joff1 = joff0 + (size_t)64 * K;
  const int dofs = tid * 8;
  const int KT = K / TK;

  // prologue: stage A/X(0) into buffer 0 (stays in flight until first vmcnt)
  gl_lds16(Ap, &As[0][0] + dofs);
  gl_lds16(Ap + rstep, &As[0][0] + 2048 + dofs);
  if constexpr (DUAL) {
    gl_lds16(Xp, &Xs[0] + dofs);
    gl_lds16(Xp + rstep, &Xs[0] + 2048 + dofs);
  }

  for (int kt = 0; kt < KT; ++kt) {
    const int kb = kt & 1;
    // stage W(kt) (readers of the previous W finished at last bottom barrier)
    gl_lds16(Wl + joff0 + kt * TK, Ls + dofs);
    gl_lds16(Wl + joff1 + kt * TK, Ls + 2048 + dofs);
    if constexpr (DUAL) {
      gl_lds16(Wr + joff0 + kt * TK, Rs + dofs);
      gl_lds16(Wr + joff1 + kt * TK, Rs + 2048 + dofs);
    }
    // prefetch A/X(kt+1) into the other buffer
    if (kt + 1 < KT) {
      const u16* Apn = Ap + kstep;
      gl_lds16(Apn, &As[kb ^ 1][0] + dofs);
      gl_lds16(Apn + rstep, &As[kb ^ 1][0] + 2048 + dofs);
      if constexpr (DUAL) {
        const u16* Xpn = Xp + kstep;
        gl_lds16(Xpn, &Xs[(kb ^ 1) * TM * TK] + dofs);
        gl_lds16(Xpn + rstep, &Xs[(kb ^ 1) * TM * TK] + 2048 + dofs);
        asm volatile("s_waitcnt vmcnt(4)" ::: "memory");
      } else {
        asm volatile("s_waitcnt vmcnt(2)" ::: "memory");
      }
    } else {
      asm volatile("s_waitcnt vmcnt(0)" ::: "memory");
    }
    __builtin_amdgcn_s_barrier();

    const u16* Asb = &As[kb][0];
    {
      short8 af[4], lf[4];
#pragma unroll
      for (int t = 0; t < 4; ++t) {
        af[t] = *(const short8*)(Asb + (wm + t * 16 + lr) * TK + quad * 8);
        lf[t] = *(const short8*)(Ls + (wn + t * 16 + lr) * TK + quad * 8);
      }
#pragma unroll
      for (int ti = 0; ti < 4; ++ti)
#pragma unroll
        for (int tj = 0; tj < 4; ++tj)
          acc[ti][tj] = __builtin_amdgcn_mfma_f32_16x16x32_bf16(
              af[ti], lf[tj], acc[ti][tj], 0, 0, 0);
    }
    if constexpr (DUAL) {
      const u16* Xsb = &Xs[kb * TM * TK];
      short8 xf[4], rf[4];
#pragma unroll
      for (int t = 0; t < 4; ++t) {
        xf[t] = *(const short8*)(Xsb + (wm + t * 16 + lr) * TK + quad * 8);
        rf[t] = *(const short8*)(Rs + (wn + t * 16 + lr) * TK + quad * 8);
      }
#pragma unroll
      for (int ti = 0; ti < 4; ++ti)
#pragma unroll
        for (int tj = 0; tj < 4; ++tj)
          acc[ti][tj] = __builtin_amdgcn_mfma_f32_16x16x32_bf16(
              xf[ti], rf[tj], acc[ti][tj], 0, 0, 0);
    }
    // all frag ds_reads must complete before next iter's W overwrite
    asm volatile("s_waitcnt lgkmcnt(0)" ::: "memory");
    __builtin_amdgcn_sched_barrier(0);
    __builtin_amdgcn_s_barrier();

    Ap += kstep;
    if constexpr (DUAL) Xp += kstep;
  }

  // epilogue: C/D layout col=lane&15, row=quad*4+reg (m89-verified)
  if constexpr (OUTMODE == 0) {
    int glo = batch[m0];
    int lastrow = m0 + TM - 1;
    bool fast = (lastrow < N_NODES) && (batch[lastrow] == glo);
#pragma unroll
    for (int tj = 0; tj < 4; ++tj) {
      int gcol = j0 + wn + tj * 16 + lr;
      float bv = bias[gcol];
      float s = 0.f, q = 0.f;
#pragma unroll
      for (int ti = 0; ti < 4; ++ti) {
        f32x4 v = acc[ti][tj];
        int rbase = m0 + wm + ti * 16 + quad * 4;
        if (fast) {
#pragma unroll
          for (int r = 0; r < 4; ++r) {
            float val = v[r] + bv;
            ((u16*)C0)[(size_t)(rbase + r) * H_DIM + gcol] = f2b(val);
            s += val; q += val * val;
          }
        } else {
          if (rbase + 3 < N_NODES && batch[rbase] == batch[rbase + 3]) {
            float s4 = 0.f, q4 = 0.f;
#pragma unroll
            for (int r = 0; r < 4; ++r) {
              float val = v[r] + bv;
              ((u16*)C0)[(size_t)(rbase + r) * H_DIM + gcol] = f2b(val);
              s4 += val; q4 += val * val;
            }
            int g = batch[rbase];
            atomicAdd(&ssum[g * H_DIM + gcol], s4);
            atomicAdd(&ssq[g * H_DIM + gcol], q4);
          } else {
#pragma unroll
            for (int r = 0; r < 4; ++r) {
              int grow = rbase + r;
              if (grow < N_NODES) {
                float val = v[r] + bv;
                ((u16*)C0)[(size_t)grow * H_DIM + gcol] = f2b(val);
                int g = batch[grow];
                atomicAdd(&ssum[g * H_DIM + gcol], val);
                atomicAdd(&ssq[g * H_DIM + gcol], val * val);
              }
            }
          }
        }
      }
      if (fast) {
        s += __shfl_xor(s, 16); s += __shfl_xor(s, 32);
        q += __shfl_xor(q, 16); q += __shfl_xor(q, 32);
        if (quad == 0) {
          atomicAdd(&ssum[glo * H_DIM + gcol], s);
          atomicAdd(&ssq[glo * H_DIM + gcol], q);
        }
      }
    }
  } else {
#pragma unroll
    for (int tj = 0; tj < 4; ++tj) {
      int gcol = j0 + wn + tj * 16 + lr;
#pragma unroll
      for (int ti = 0; ti < 4; ++ti) {
        f32x4 v = acc[ti][tj];
#pragma unroll
        for (int r = 0; r < 4; ++r) {
          int grow = m0 + wm + ti * 16 + quad * 4 + r;
          if (gcol < 128)
            ((u16*)C0)[(size_t)grow * 128 + gcol] = f2b(v[r]);
          else
            ((float*)C1)[(size_t)grow * 128 + (gcol - 128)] = v[r];
        }
      }
    }
  }
}

// ---------------- GraphNorm: precompute affine, then apply+relu -------------

__global__ void k_precomp(const float* __restrict__ ssum, const float* __restrict__ ssq,
                          const float* __restrict__ inv_sz, const float* __restrict__ gw,
                          const float* __restrict__ gb, const float* __restrict__ alpha,
                          float* __restrict__ S, float* __restrict__ T) {
  int idx = blockIdx.x * blockDim.x + threadIdx.x;
  if (idx >= N_GROUPS * H_DIM) return;
  int g = idx >> 9;
  int c = idx & (H_DIM - 1);
  float is = inv_sz[g];
  float m = ssum[idx] * is;
  float a = alpha[c];
  float var = fmaxf(ssq[idx] * is - a * (2.f - a) * m * m, 0.f);
  float inv = rsqrtf(var + EPSV);
  float sc = inv * gw[c];
  S[idx] = sc;
  T[idx] = gb[c] - a * m * sc;
}

// reads row-major pre-norm GEMM output, writes normalized+relu'd h in the
// SLICED layout (16 x [M_PAD][32] u16 contiguous slices).
__global__ void k_apply(const u16* __restrict__ praw, u16* __restrict__ hs,
                        const int* __restrict__ batch,
                        const float* __restrict__ S, const float* __restrict__ T) {
  int tid = blockIdx.x * blockDim.x + threadIdx.x;
  if (tid >= N_NODES * (H_DIM / 8)) return;
  int n = tid >> 6;
  int c0 = (tid & 63) << 3;
  int g = batch[n];
  u16x8 hv = *(const u16x8*)(praw + (size_t)n * H_DIM + c0);
  u16x8 out;
#pragma unroll
  for (int j = 0; j < 8; ++j) {
    int f = c0 + j;
    float y = b2f(hv[j]) * S[g * H_DIM + f] + T[g * H_DIM + f];
    out[j] = f2b(fmaxf(y, 0.f));
  }
  *(u16x8*)(hs + ((size_t)(c0 >> 5) * M_PAD + n) * 32 + (c0 & 31)) = out;
}

// ---------------- driver ----------------

extern "C" void kernel_launch(void* const* d_in, const int* in_sizes, int n_in,
                              void* d_out, int out_size, void* d_ws, size_t ws_size,
                              hipStream_t stream) {
  const float* x = (const float*)d_in[0];
  const int* edge = (const int*)d_in[1];
  const int* batch = (const int*)d_in[2];
  const float *Wl[5], *Wr[5], *bb[5];
  for (int i = 0; i < 5; ++i) {
    Wl[i] = (const float*)d_in[3 + 3 * i];
    Wr[i] = (const float*)d_in[4 + 3 * i];
    bb[i] = (const float*)d_in[5 + 3 * i];
  }
  const float *gamma[4], *beta[4], *alpha[4];
  for (int i = 0; i < 4; ++i) {
    gamma[i] = (const float*)d_in[18 + 3 * i];
    beta[i]  = (const float*)d_in[19 + 3 * i];
    alpha[i] = (const float*)d_in[20 + 3 * i];
  }
  const int* srcv = edge;
  const int* dstv = edge + N_EDGES;

  char* base = (char*)d_ws;
  size_t off = 0;
  auto carve = [&](size_t bytes) -> char* {
    char* p = base + off;
    off = (off + bytes + 255) & ~(size_t)255;
    return p;
  };
  int* deg       = (int*)carve((size_t)N_NODES * 4);
  float* inv_deg = (float*)carve((size_t)N_NODES * 4);
  int* csr_off   = (int*)carve((size_t)(N_NODES + 1) * 4);
  int* cursor    = (int*)carve((size_t)N_NODES * 4);
  int* csr_src   = (int*)carve((size_t)N_EDGES * 4);
  int* bsum      = (int*)carve((size_t)SCAN_NBLK * 4);
  int* gstart    = (int*)carve((size_t)(N_GROUPS + 1) * 4);
  float* inv_sz  = (float*)carve((size_t)N_GROUPS * 4);
  int* perm      = (int*)carve((size_t)N_NODES * 4);
  float* stats   = (float*)carve((size_t)4 * 2 * N_GROUPS * H_DIM * 4);
  float* Sbuf    = (float*)carve((size_t)N_GROUPS * H_DIM * 4);
  float* Tbuf    = (float*)carve((size_t)N_GROUPS * H_DIM * 4);
  u16* xb        = (u16*)carve((size_t)XB_EL * 2);
  u16* aggx      = (u16*)carve((size_t)XB_EL * 2);
  u16* praw      = (u16*)carve((size_t)M_PAD * H_DIM * 2);  // pre-norm GEMM out (rm)
  u16* hsA       = (u16*)carve((size_t)M_PAD * H_DIM * 2);  // normalized h (sliced)
  u16* aggs      = (u16*)carve((size_t)M_PAD * H_DIM * 2);  // aggregated h (sliced)
  u16* wall      = (u16*)carve((size_t)WALL_EL * 2);
  (void)ws_size; (void)in_sizes; (void)n_in; (void)out_size;

  u16* w1lb = wall;
  u16* w1rb = wall + 32768;
  u16* w2lb = wall + 65536;
  u16* w2rb = wall + 327680;
  u16* w3lb = wall + 589824;
  u16* w3rb = wall + 851968;
  u16* w4lb = wall + 1114112;
  u16* w4rb = wall + 1376256;
  u16* w5cat = wall + 1638400;  // 256 x 512

  u16* Plb = aggs;  // layer-5 P split lives in the (dead) aggs region
  float* Prf = (float*)((char*)aggs + (size_t)M_PAD * 128 * 2);

  // graph preprocessing
  hipMemsetAsync(deg, 0, (size_t)N_NODES * 4, stream);
  k_deg<<<(N_EDGES + 255) / 256, 256, 0, stream>>>(dstv, deg);
  k_scan1<<<SCAN_NBLK, SCAN_BLK, 0, stream>>>(deg, csr_off, bsum);
  k_scan2_gbounds<<<2, 256, 0, stream>>>(bsum, batch, gstart, inv_sz);
  k_scan3prep<<<SCAN_NBLK, SCAN_BLK, 0, stream>>>(csr_off, bsum, deg, inv_deg, cursor);
  k_scatter<<<(N_EDGES + 255) / 256, 256, 0, stream>>>(srcv, dstv, cursor, csr_src);
  k_wsort<<<256, 256, 0, stream>>>(deg, perm);

  WcSrc ws_src;
  ws_src.p[0] = Wl[0]; ws_src.p[1] = Wr[0];
  ws_src.p[2] = Wl[1]; ws_src.p[3] = Wr[1];
  ws_src.p[4] = Wl[2]; ws_src.p[5] = Wr[2];
  ws_src.p[6] = Wl[3]; ws_src.p[7] = Wr[3];
  ws_src.p[8] = Wl[4]; ws_src.p[9] = Wr[4];
  k_convert_all<<<(XB_EL + WALL_EL + 255) / 256, 256, 0, stream>>>(x, ws_src, xb, wall);

  hipMemsetAsync(stats, 0, (size_t)4 * 2 * N_GROUPS * H_DIM * 4, stream);

  const int nblk_main = M_TILES * 4;  // JB=4
  const int nblk_l5   = M_TILES * 2;  // JB=2

  auto norm = [&](int l) {
    float* ss = stats + (size_t)l * 2 * N_GROUPS * H_DIM;
    float* sq = ss + N_GROUPS * H_DIM;
    k_precomp<<<(N_GROUPS * H_DIM + 255) / 256, 256, 0, stream>>>(
        ss, sq, inv_sz, gamma[l], beta[l], alpha[l], Sbuf, Tbuf);
    k_apply<<<(N_NODES * (H_DIM / 8) + 255) / 256, 256, 0, stream>>>(
        praw, hsA, batch, Sbuf, Tbuf);
  };
  auto stat_ptr = [&](int l) { return stats + (size_t)l * 2 * N_GROUPS * H_DIM; };
  auto agg = [&]() {
    k_agg_slice<<<AGG_BLKS, 256, 0, stream>>>(hsA, csr_off, csr_src, inv_deg, perm, aggs, 0);
    k_agg_slice<<<AGG_BLKS, 256, 0, stream>>>(hsA, csr_off, csr_src, inv_deg, perm, aggs, 1);
  };

  // layer 1 (K = 64 padded, row-major operands)
  k_agg_small<<<N_NODES, 64, 0, stream>>>(xb, csr_off, csr_src, inv_deg, aggx);
  k_gemm_mfma<4, true, 0, false><<<nblk_main, 256, 0, stream>>>(
      aggx, xb, w1lb, w1rb, bb[0], praw, nullptr, batch,
      stat_ptr(0), stat_ptr(0) + N_GROUPS * H_DIM, K1PAD);
  norm(0);

  // layers 2..4: sliced gather (one slice-set per dispatch) + sliced GEMM
  agg();
  k_gemm_mfma<4, true, 0, true><<<nblk_main, 256, 0, stream>>>(
      aggs, hsA, w2lb, w2rb, bb[1], praw, nullptr, batch,
      stat_ptr(1), stat_ptr(1) + N_GROUPS * H_DIM, H_DIM);
  norm(1);

  agg();
  k_gemm_mfma<4, true, 0, true><<<nblk_main, 256, 0, stream>>>(
      aggs, hsA, w3lb, w3rb, bb[2], praw, nullptr, batch,
      stat_ptr(2), stat_ptr(2) + N_GROUPS * H_DIM, H_DIM);
  norm(2);

  agg();
  k_gemm_mfma<4, true, 0, true><<<nblk_main, 256, 0, stream>>>(
      aggs, hsA, w4lb, w4rb, bb[3], praw, nullptr, batch,
      stat_ptr(3), stat_ptr(3) + N_GROUPS * H_DIM, H_DIM);
  norm(3);

  // layer 5 via linearity: P = h @ [W5l|W5r]^T (J=256), then
  // out = inv_deg * segsum(Pl[src]) + Pr + b5
  k_gemm_mfma<2, false, 1, true><<<nblk_l5, 256, 0, stream>>>(
      hsA, nullptr, w5cat, nullptr, nullptr, Plb, Prf, nullptr, nullptr, nullptr, H_DIM);
  k_agg_final<<<(N_NODES + 7) / 8, 256, 0, stream>>>(
      Plb, Prf, csr_off, csr_src, inv_deg, bb[4], (float*)d_out);
}

// Round 7
// 1021.640 us; speedup vs baseline: 1.0565x; 1.0565x over previous
//
#include <hip/hip_runtime.h>
#include <cstddef>
#include <cstdint>

#define N_NODES 50000
#define N_EDGES 800000
#define F_IN 50
#define K1PAD 64
#define H_DIM 512
#define O_DIM 121
#define N_GROUPS 20
#define EPSV 1e-5f
#define M_PAD 50176   // 392 * 128
#define M_TILES 392

#define SCAN_BLK 256
#define SCAN_NBLK ((N_NODES + SCAN_BLK - 1) / SCAN_BLK)  // 196
#define WALL_EL 1769472
#define XB_EL (M_PAD * K1PAD)

typedef unsigned short u16;
typedef __attribute__((ext_vector_type(8))) short short8;          // 8 bf16 (4 VGPRs)
typedef __attribute__((ext_vector_type(8))) unsigned short u16x8;  // 16B vector load
typedef __attribute__((ext_vector_type(4))) float f32x4;

__device__ __forceinline__ float b2f(u16 u) {
  union { unsigned int i; float f; } v; v.i = ((unsigned int)u) << 16; return v.f;
}
__device__ __forceinline__ u16 f2b(float f) {
  union { float f; unsigned int i; } v; v.f = f;
  unsigned int x = v.i;
  return (u16)((x + 0x7fffu + ((x >> 16) & 1u)) >> 16);  // RNE
}

__device__ __forceinline__ void gl_lds16(const void* g, void* l) {
  __builtin_amdgcn_global_load_lds(
      (__attribute__((address_space(1))) void*)(g),
      (__attribute__((address_space(3))) void*)(l), 16, 0, 0);
}

// ---------------- graph preprocessing ----------------

__global__ void k_deg(const int* __restrict__ dst, int* __restrict__ deg) {
  int e = blockIdx.x * blockDim.x + threadIdx.x;
  if (e < N_EDGES) atomicAdd(&deg[dst[e]], 1);
}

__global__ void k_scan1(const int* __restrict__ deg, int* __restrict__ off,
                        int* __restrict__ bsum) {
  __shared__ int buf[SCAN_BLK];
  int gid = blockIdx.x * SCAN_BLK + threadIdx.x;
  buf[threadIdx.x] = (gid < N_NODES) ? deg[gid] : 0;
  __syncthreads();
  for (int d = 1; d < SCAN_BLK; d <<= 1) {
    int t = (threadIdx.x >= d) ? buf[threadIdx.x - d] : 0;
    __syncthreads();
    buf[threadIdx.x] += t;
    __syncthreads();
  }
  if (gid < N_NODES) off[gid + 1] = buf[threadIdx.x];
  if (threadIdx.x == SCAN_BLK - 1) bsum[blockIdx.x] = buf[threadIdx.x];
}

// block 0: scan of block sums; block 1: group bounds from sorted batch
__global__ void k_scan2_gbounds(int* __restrict__ bsum, const int* __restrict__ batch,
                                int* __restrict__ gstart, float* __restrict__ inv_sz) {
  int t = threadIdx.x;
  if (blockIdx.x == 0) {
    __shared__ int buf[256];
    buf[t] = (t < SCAN_NBLK) ? bsum[t] : 0;
    __syncthreads();
    for (int d = 1; d < 256; d <<= 1) {
      int v = (t >= d) ? buf[t - d] : 0;
      __syncthreads();
      buf[t] += v;
      __syncthreads();
    }
    if (t < SCAN_NBLK) bsum[t] = buf[t];
  } else {
    if (t <= N_GROUPS) {
      int lo = 0, hi = N_NODES;
      while (lo < hi) {
        int mid = (lo + hi) >> 1;
        if (batch[mid] < t) lo = mid + 1; else hi = mid;
      }
      gstart[t] = lo;
    }
    __syncthreads();
    if (t < N_GROUPS) {
      int sz = gstart[t + 1] - gstart[t];
      inv_sz[t] = 1.0f / (float)max(sz, 1);
    }
  }
}

__global__ void k_scan3prep(int* __restrict__ off, const int* __restrict__ bsum,
                            const int* __restrict__ deg, float* __restrict__ inv_deg,
                            int* __restrict__ cursor) {
  int gid = blockIdx.x * SCAN_BLK + threadIdx.x;
  if (gid < N_NODES) {
    int add = (blockIdx.x > 0) ? bsum[blockIdx.x - 1] : 0;
    int v = off[gid + 1] + add;
    off[gid + 1] = v;
    if (gid + 1 < N_NODES) cursor[gid + 1] = v;
    inv_deg[gid] = 1.0f / (float)max(deg[gid], 1);
  }
  if (gid == 0) { off[0] = 0; cursor[0] = 0; }
}

__global__ void k_scatter(const int* __restrict__ src, const int* __restrict__ dst,
                          int* __restrict__ cursor, int* __restrict__ csr_src) {
  int e = blockIdx.x * blockDim.x + threadIdx.x;
  if (e < N_EDGES) {
    int p = atomicAdd(&cursor[dst[e]], 1);
    csr_src[p] = src[e];
  }
}

// ---------------- conversions (x pad + all weights, one launch) -------------
struct WcSrc { const float* p[10]; };
__global__ void k_convert_all(const float* __restrict__ x, WcSrc s,
                              u16* __restrict__ xb, u16* __restrict__ wall) {
  int idx = blockIdx.x * blockDim.x + threadIdx.x;
  if (idx < XB_EL) {
    int r = idx >> 6, c = idx & (K1PAD - 1);
    float v = (r < N_NODES && c < F_IN) ? x[r * F_IN + c] : 0.f;
    xb[idx] = f2b(v);
    return;
  }
  idx -= XB_EL;
  if (idx >= WALL_EL) return;
  const int seg_start[10] = {0, 32768, 65536, 327680, 589824, 851968,
                             1114112, 1376256, 1638400, 1703936};
  const int jr[10]  = {512, 512, 512, 512, 512, 512, 512, 512, 121, 121};
  const int kin[10] = {50, 50, 512, 512, 512, 512, 512, 512, 512, 512};
  const int ksh[10] = {6, 6, 9, 9, 9, 9, 9, 9, 9, 9};
  int sgi = 0;
#pragma unroll
  for (int t = 1; t < 10; ++t)
    if (idx >= seg_start[t]) sgi = t;
  int local = idx - seg_start[sgi];
  int j = local >> ksh[sgi];
  int k = local & ((1 << ksh[sgi]) - 1);
  float v = (j < jr[sgi] && k < kin[sgi]) ? s.p[sgi][j * kin[sgi] + k] : 0.f;
  wall[idx] = f2b(v);
}

// ---------------- aggregation ----------------

__global__ void k_agg_small(const u16* __restrict__ xb, const int* __restrict__ off,
                            const int* __restrict__ srcs, const float* __restrict__ inv_deg,
                            u16* __restrict__ agg) {
  int n = blockIdx.x;
  int f = threadIdx.x;  // 0..63
  int b = off[n], e = off[n + 1];
  float s = 0.f;
  for (int i = b; i < e; ++i) s += b2f(xb[(size_t)srcs[i] * K1PAD + f]);
  agg[(size_t)n * K1PAD + f] = f2b(s * inv_deg[n]);
}

// layers 2..4 aggregation, XCD-sliced. h stored SLICED: 16 regions of
// [M_PAD][32] u16 (3.2MB each); slice s = xcd*2+ph processed only by blocks
// on XCD s>>1 (blockIdx&7 -> XCD round-robin).
// ONE PHASE PER DISPATCH (r4 lesson: both phases resident -> 2 slices + CSR
// > 4MB L2 -> thrash). NATURAL node order (r3/r6 lessons: any reordering
// perm broke CSR/write locality and cost more than the divergence it saved).
// 8-edge unroll: MLP 8 halves the L2-latency rounds for a deg~16 node.
#define AGG_BLKS 2048  // 256 chunks x 8 XCDs
__global__ __launch_bounds__(256) void k_agg_slice(
    const u16* __restrict__ hs, const int* __restrict__ off,
    const int* __restrict__ srcs, const float* __restrict__ inv_deg,
    u16* __restrict__ aggs, int ph) {
  const int xcd = blockIdx.x & 7;
  const int chunk = blockIdx.x >> 3;                 // 0..255
  const int nchunk = AGG_BLKS / 8;                   // 256
  const int per = (N_NODES + nchunk - 1) / nchunk;   // 196
  const int p0 = chunk * per;
  const int p1 = min(p0 + per, N_NODES);
  const int grp = threadIdx.x >> 2;       // 0..63 node-groups per block
  const int sub = (threadIdx.x & 3) * 8;  // u16 offset of this lane's 16B
  const int s = xcd * 2 + ph;
  const u16* hsl = hs + (size_t)s * M_PAD * 32 + sub;
  u16* asl = aggs + (size_t)s * M_PAD * 32 + sub;
  for (int n = p0 + grp; n < p1; n += 64) {
    int b = off[n], e = off[n + 1];
    float a[8] = {};
    int i = b;
    for (; i + 8 <= e; i += 8) {
      u16x8 v0 = *(const u16x8*)(hsl + (size_t)srcs[i + 0] * 32);
      u16x8 v1 = *(const u16x8*)(hsl + (size_t)srcs[i + 1] * 32);
      u16x8 v2 = *(const u16x8*)(hsl + (size_t)srcs[i + 2] * 32);
      u16x8 v3 = *(const u16x8*)(hsl + (size_t)srcs[i + 3] * 32);
      u16x8 v4 = *(const u16x8*)(hsl + (size_t)srcs[i + 4] * 32);
      u16x8 v5 = *(const u16x8*)(hsl + (size_t)srcs[i + 5] * 32);
      u16x8 v6 = *(const u16x8*)(hsl + (size_t)srcs[i + 6] * 32);
      u16x8 v7 = *(const u16x8*)(hsl + (size_t)srcs[i + 7] * 32);
#pragma unroll
      for (int j = 0; j < 8; ++j)
        a[j] += ((b2f(v0[j]) + b2f(v1[j])) + (b2f(v2[j]) + b2f(v3[j]))) +
                ((b2f(v4[j]) + b2f(v5[j])) + (b2f(v6[j]) + b2f(v7[j])));
    }
    for (; i + 4 <= e; i += 4) {
      u16x8 v0 = *(const u16x8*)(hsl + (size_t)srcs[i + 0] * 32);
      u16x8 v1 = *(const u16x8*)(hsl + (size_t)srcs[i + 1] * 32);
      u16x8 v2 = *(const u16x8*)(hsl + (size_t)srcs[i + 2] * 32);
      u16x8 v3 = *(const u16x8*)(hsl + (size_t)srcs[i + 3] * 32);
#pragma unroll
      for (int j = 0; j < 8; ++j)
        a[j] += (b2f(v0[j]) + b2f(v1[j])) + (b2f(v2[j]) + b2f(v3[j]));
    }
    for (; i < e; ++i) {
      u16x8 v0 = *(const u16x8*)(hsl + (size_t)srcs[i] * 32);
#pragma unroll
      for (int j = 0; j < 8; ++j) a[j] += b2f(v0[j]);
    }
    float w = inv_deg[n];
    u16x8 r;
#pragma unroll
    for (int j = 0; j < 8; ++j) r[j] = f2b(a[j] * w);
    *(u16x8*)(asl + (size_t)n * 32) = r;
  }
}

// layer 5 final: out[n] = inv_deg[n]*sum(Pl[src]) + Pr[n] + bias (121 cols)
__global__ __launch_bounds__(256) void k_agg_final(
    const u16* __restrict__ Plb, const float* __restrict__ Prf,
    const int* __restrict__ off, const int* __restrict__ srcs,
    const float* __restrict__ inv_deg, const float* __restrict__ bias,
    float* __restrict__ out) {
  int n = blockIdx.x * 8 + (threadIdx.x >> 5);
  if (n >= N_NODES) return;
  int l = threadIdx.x & 31;
  int c0 = l * 4;
  int b = off[n], e = off[n + 1];
  float a0 = 0.f, a1 = 0.f, a2 = 0.f, a3 = 0.f;
  int i = b;
  for (; i + 2 <= e; i += 2) {
    ushort4 v0 = ((const ushort4*)(Plb + (size_t)srcs[i] * 128))[l];
    ushort4 v1 = ((const ushort4*)(Plb + (size_t)srcs[i + 1] * 128))[l];
    a0 += b2f(v0.x) + b2f(v1.x); a1 += b2f(v0.y) + b2f(v1.y);
    a2 += b2f(v0.z) + b2f(v1.z); a3 += b2f(v0.w) + b2f(v1.w);
  }
  if (i < e) {
    ushort4 v0 = ((const ushort4*)(Plb + (size_t)srcs[i] * 128))[l];
    a0 += b2f(v0.x); a1 += b2f(v0.y); a2 += b2f(v0.z); a3 += b2f(v0.w);
  }
  float w = inv_deg[n];
  float4 pr = ((const float4*)(Prf + (size_t)n * 128))[l];
  float r0 = a0 * w + pr.x, r1 = a1 * w + pr.y;
  float r2 = a2 * w + pr.z, r3 = a3 * w + pr.w;
  size_t ob = (size_t)n * O_DIM;
  if (c0 + 0 < O_DIM) out[ob + c0 + 0] = r0 + bias[c0 + 0];
  if (c0 + 1 < O_DIM) out[ob + c0 + 1] = r1 + bias[c0 + 1];
  if (c0 + 2 < O_DIM) out[ob + c0 + 2] = r2 + bias[c0 + 2];
  if (c0 + 3 < O_DIM) out[ob + c0 + 3] = r3 + bias[c0 + 3];
}

// ---------------- MFMA GEMM ----------------
// DUAL(OUTMODE 0): C = A*Wl^T + X*Wr^T + b, bf16 out [*, 512]; GraphNorm
//   stats fused in epilogue. !DUAL(OUTMODE 1): P = A*Wl^T split bf16/f32.
// SL: A/X in the 16x[M_PAD][32] sliced layout.
// K-loop: r5's simple 2-barrier form (r6's counted-vmcnt pipeline regressed:
//   LDS 48KB + VGPR 80 cut occupancy more than the pipeline gained).
// EPILOGUE (r6 fix target: WRITE_SIZE 83MB vs 51MB logical = 1.6x partial-
//   line write amplification from 64 scattered u16 stores/thread): stage the
//   wave's 64x64 bf16 tile into its dead 8KB of staging LDS, XOR-swizzled
//   (byte ^= ((row>>2)&3)<<5 -> b16 writes conflict-free, b128 reads at
//   minimum aliasing), then read back row-contiguous and store 8 coalesced
//   16B/lane stores covering full 128B segments.

#define TM 128
#define TK 32

template <int JB, bool DUAL, int OUTMODE, bool SL>
__global__ __launch_bounds__(256, 4) void k_gemm_mfma(
    const u16* __restrict__ A, const u16* __restrict__ X,
    const u16* __restrict__ Wl, const u16* __restrict__ Wr,
    const float* __restrict__ bias, void* __restrict__ C0,
    void* __restrict__ C1, const int* __restrict__ batch,
    float* __restrict__ ssum, float* __restrict__ ssq, int K) {
  __shared__ u16 smem[DUAL ? 16384 : 8192];
  u16* As = smem;
  u16* Ls = smem + 4096;
  u16* Xs = DUAL ? smem + 8192 : smem;
  u16* Rs = DUAL ? smem + 12288 : smem;

  int id = blockIdx.x;
  const int nfull = (M_TILES >> 3) * 8 * JB;
  int m_t, j_t;
  if (id < nfull) {
    m_t = (id / (8 * JB)) * 8 + (id & 7);
    j_t = (id >> 3) & (JB - 1);
  } else {
    int rem = id - nfull;
    const int nrem = (M_TILES & 7) ? (M_TILES & 7) : 1;
    m_t = (M_TILES & ~7) + rem % nrem;
    j_t = rem / nrem;
  }
  int m0 = m_t * TM;
  int j0 = j_t * 128;

  int tid = threadIdx.x;
  int lane = tid & 63;
  int wave = tid >> 6;
  int quad = lane >> 4;
  int lr = lane & 15;
  int wm = (wave & 1) * 64;
  int wn = (wave >> 1) * 64;

  f32x4 acc[4][4] = {};

  int sr = tid >> 2;
  int sc = (tid & 3) * 8;
  const size_t kstep = SL ? (size_t)M_PAD * 32 : (size_t)TK;
  const size_t rstep = SL ? (size_t)64 * 32 : (size_t)64 * K;
  const u16* Ap = A + (SL ? (size_t)(m0 + sr) * 32 + sc
                          : (size_t)(m0 + sr) * K + sc);
  const u16* Xp = nullptr;
  if constexpr (DUAL)
    Xp = X + (SL ? (size_t)(m0 + sr) * 32 + sc
                 : (size_t)(m0 + sr) * K + sc);
  size_t joff0 = (size_t)(j0 + sr) * K + sc;
  size_t joff1 = joff0 + (size_t)64 * K;
  const int dofs = tid * 8;

  for (int k0 = 0; k0 < K; k0 += TK) {
    __syncthreads();
    gl_lds16(Ap, As + dofs);
    gl_lds16(Ap + rstep, As + 2048 + dofs);
    gl_lds16(Wl + joff0 + k0, Ls + dofs);
    gl_lds16(Wl + joff1 + k0, Ls + 2048 + dofs);
    if constexpr (DUAL) {
      gl_lds16(Xp, Xs + dofs);
      gl_lds16(Xp + rstep, Xs + 2048 + dofs);
      gl_lds16(Wr + joff0 + k0, Rs + dofs);
      gl_lds16(Wr + joff1 + k0, Rs + 2048 + dofs);
      Xp += kstep;
    }
    Ap += kstep;
    __syncthreads();
    {
      short8 af[4], lf[4];
#pragma unroll
      for (int t = 0; t < 4; ++t) {
        af[t] = *(const short8*)(As + (wm + t * 16 + lr) * TK + quad * 8);
        lf[t] = *(const short8*)(Ls + (wn + t * 16 + lr) * TK + quad * 8);
      }
#pragma unroll
      for (int ti = 0; ti < 4; ++ti)
#pragma unroll
        for (int tj = 0; tj < 4; ++tj)
          acc[ti][tj] = __builtin_amdgcn_mfma_f32_16x16x32_bf16(
              af[ti], lf[tj], acc[ti][tj], 0, 0, 0);
    }
    if constexpr (DUAL) {
      short8 xf[4], rf[4];
#pragma unroll
      for (int t = 0; t < 4; ++t) {
        xf[t] = *(const short8*)(Xs + (wm + t * 16 + lr) * TK + quad * 8);
        rf[t] = *(const short8*)(Rs + (wn + t * 16 + lr) * TK + quad * 8);
      }
#pragma unroll
      for (int ti = 0; ti < 4; ++ti)
#pragma unroll
        for (int tj = 0; tj < 4; ++tj)
          acc[ti][tj] = __builtin_amdgcn_mfma_f32_16x16x32_bf16(
              xf[ti], rf[tj], acc[ti][tj], 0, 0, 0);
    }
  }

  // epilogue: C/D layout col=lane&15, row=quad*4+reg (m89-verified)
  if constexpr (OUTMODE == 0) {
    __syncthreads();  // all waves done with staging LDS reads -> reuse as wbuf
    u16* wbuf = smem + wave * 4096;  // wave-private 64x64 u16, XOR-swizzled
    int glo = batch[m0];
    int lastrow = m0 + TM - 1;
    bool fast = (lastrow < N_NODES) && (batch[lastrow] == glo);
#pragma unroll
    for (int tj = 0; tj < 4; ++tj) {
      int gcol = j0 + wn + tj * 16 + lr;
      int cl = tj * 16 + lr;  // local col
      float bv = bias[gcol];
      float s = 0.f, q = 0.f;
#pragma unroll
      for (int ti = 0; ti < 4; ++ti) {
        f32x4 v = acc[ti][tj];
        int rbase = m0 + wm + ti * 16 + quad * 4;
        int rl0 = ti * 16 + quad * 4;  // local row base
        if (fast) {
#pragma unroll
          for (int r = 0; r < 4; ++r) {
            float val = v[r] + bv;
            int rl = rl0 + r;
            int bo = (rl * 128 + cl * 2) ^ (((rl >> 2) & 3) << 5);
            *(u16*)((char*)wbuf + bo) = f2b(val);
            s += val; q += val * val;
          }
        } else {
          if (rbase + 3 < N_NODES && batch[rbase] == batch[rbase + 3]) {
            float s4 = 0.f, q4 = 0.f;
#pragma unroll
            for (int r = 0; r < 4; ++r) {
              float val = v[r] + bv;
              int rl = rl0 + r;
              int bo = (rl * 128 + cl * 2) ^ (((rl >> 2) & 3) << 5);
              *(u16*)((char*)wbuf + bo) = f2b(val);
              s4 += val; q4 += val * val;
            }
            int g = batch[rbase];
            atomicAdd(&ssum[g * H_DIM + gcol], s4);
            atomicAdd(&ssq[g * H_DIM + gcol], q4);
          } else {
#pragma unroll
            for (int r = 0; r < 4; ++r) {
              int grow = rbase + r;
              float val = v[r] + bv;
              int rl = rl0 + r;
              int bo = (rl * 128 + cl * 2) ^ (((rl >> 2) & 3) << 5);
              *(u16*)((char*)wbuf + bo) = f2b(val);  // padding rows land in praw pad
              if (grow < N_NODES) {
                int g = batch[grow];
                atomicAdd(&ssum[g * H_DIM + gcol], val);
                atomicAdd(&ssq[g * H_DIM + gcol], val * val);
              }
            }
          }
        }
      }
      if (fast) {
        s += __shfl_xor(s, 16); s += __shfl_xor(s, 32);
        q += __shfl_xor(q, 16); q += __shfl_xor(q, 32);
        if (quad == 0) {
          atomicAdd(&ssum[glo * H_DIM + gcol], s);
          atomicAdd(&ssq[glo * H_DIM + gcol], q);
        }
      }
    }
    __syncthreads();  // wave's LDS writes complete before read-back
#pragma unroll
    for (int it = 0; it < 8; ++it) {
      int rl = it * 8 + (lane >> 3);
      int c0 = (lane & 7) * 8;
      int bo = (rl * 128 + c0 * 2) ^ (((rl >> 2) & 3) << 5);
      u16x8 vv = *(const u16x8*)((const char*)wbuf + bo);
      *(u16x8*)((u16*)C0 + (size_t)(m0 + wm + rl) * H_DIM + (j0 + wn + c0)) = vv;
    }
  } else {
#pragma unroll
    for (int tj = 0; tj < 4; ++tj) {
      int gcol = j0 + wn + tj * 16 + lr;
#pragma unroll
      for (int ti = 0; ti < 4; ++ti) {
        f32x4 v = acc[ti][tj];
#pragma unroll
        for (int r = 0; r < 4; ++r) {
          int grow = m0 + wm + ti * 16 + quad * 4 + r;
          if (gcol < 128)
            ((u16*)C0)[(size_t)grow * 128 + gcol] = f2b(v[r]);
          else
            ((float*)C1)[(size_t)grow * 128 + (gcol - 128)] = v[r];
        }
      }
    }
  }
}

// ---------------- GraphNorm: precompute affine, then apply+relu -------------

__global__ void k_precomp(const float* __restrict__ ssum, const float* __restrict__ ssq,
                          const float* __restrict__ inv_sz, const float* __restrict__ gw,
                          const float* __restrict__ gb, const float* __restrict__ alpha,
                          float* __restrict__ S, float* __restrict__ T) {
  int idx = blockIdx.x * blockDim.x + threadIdx.x;
  if (idx >= N_GROUPS * H_DIM) return;
  int g = idx >> 9;
  int c = idx & (H_DIM - 1);
  float is = inv_sz[g];
  float m = ssum[idx] * is;
  float a = alpha[c];
  float var = fmaxf(ssq[idx] * is - a * (2.f - a) * m * m, 0.f);
  float inv = rsqrtf(var + EPSV);
  float sc = inv * gw[c];
  S[idx] = sc;
  T[idx] = gb[c] - a * m * sc;
}

// reads row-major pre-norm GEMM output, writes normalized+relu'd h in the
// SLICED layout (16 x [M_PAD][32] u16 contiguous slices).
__global__ void k_apply(const u16* __restrict__ praw, u16* __restrict__ hs,
                        const int* __restrict__ batch,
                        const float* __restrict__ S, const float* __restrict__ T) {
  int tid = blockIdx.x * blockDim.x + threadIdx.x;
  if (tid >= N_NODES * (H_DIM / 8)) return;
  int n = tid >> 6;
  int c0 = (tid & 63) << 3;
  int g = batch[n];
  u16x8 hv = *(const u16x8*)(praw + (size_t)n * H_DIM + c0);
  u16x8 out;
#pragma unroll
  for (int j = 0; j < 8; ++j) {
    int f = c0 + j;
    float y = b2f(hv[j]) * S[g * H_DIM + f] + T[g * H_DIM + f];
    out[j] = f2b(fmaxf(y, 0.f));
  }
  *(u16x8*)(hs + ((size_t)(c0 >> 5) * M_PAD + n) * 32 + (c0 & 31)) = out;
}

// ---------------- driver ----------------

extern "C" void kernel_launch(void* const* d_in, const int* in_sizes, int n_in,
                              void* d_out, int out_size, void* d_ws, size_t ws_size,
                              hipStream_t stream) {
  const float* x = (const float*)d_in[0];
  const int* edge = (const int*)d_in[1];
  const int* batch = (const int*)d_in[2];
  const float *Wl[5], *Wr[5], *bb[5];
  for (int i = 0; i < 5; ++i) {
    Wl[i] = (const float*)d_in[3 + 3 * i];
    Wr[i] = (const float*)d_in[4 + 3 * i];
    bb[i] = (const float*)d_in[5 + 3 * i];
  }
  const float *gamma[4], *beta[4], *alpha[4];
  for (int i = 0; i < 4; ++i) {
    gamma[i] = (const float*)d_in[18 + 3 * i];
    beta[i]  = (const float*)d_in[19 + 3 * i];
    alpha[i] = (const float*)d_in[20 + 3 * i];
  }
  const int* srcv = edge;
  const int* dstv = edge + N_EDGES;

  char* base = (char*)d_ws;
  size_t off = 0;
  auto carve = [&](size_t bytes) -> char* {
    char* p = base + off;
    off = (off + bytes + 255) & ~(size_t)255;
    return p;
  };
  int* deg       = (int*)carve((size_t)N_NODES * 4);
  float* inv_deg = (float*)carve((size_t)N_NODES * 4);
  int* csr_off   = (int*)carve((size_t)(N_NODES + 1) * 4);
  int* cursor    = (int*)carve((size_t)N_NODES * 4);
  int* csr_src   = (int*)carve((size_t)N_EDGES * 4);
  int* bsum      = (int*)carve((size_t)SCAN_NBLK * 4);
  int* gstart    = (int*)carve((size_t)(N_GROUPS + 1) * 4);
  float* inv_sz  = (float*)carve((size_t)N_GROUPS * 4);
  float* stats   = (float*)carve((size_t)4 * 2 * N_GROUPS * H_DIM * 4);
  float* Sbuf    = (float*)carve((size_t)N_GROUPS * H_DIM * 4);
  float* Tbuf    = (float*)carve((size_t)N_GROUPS * H_DIM * 4);
  u16* xb        = (u16*)carve((size_t)XB_EL * 2);
  u16* aggx      = (u16*)carve((size_t)XB_EL * 2);
  u16* praw      = (u16*)carve((size_t)M_PAD * H_DIM * 2);  // pre-norm GEMM out (rm)
  u16* hsA       = (u16*)carve((size_t)M_PAD * H_DIM * 2);  // normalized h (sliced)
  u16* aggs      = (u16*)carve((size_t)M_PAD * H_DIM * 2);  // aggregated h (sliced)
  u16* wall      = (u16*)carve((size_t)WALL_EL * 2);
  (void)ws_size; (void)in_sizes; (void)n_in; (void)out_size;

  u16* w1lb = wall;
  u16* w1rb = wall + 32768;
  u16* w2lb = wall + 65536;
  u16* w2rb = wall + 327680;
  u16* w3lb = wall + 589824;
  u16* w3rb = wall + 851968;
  u16* w4lb = wall + 1114112;
  u16* w4rb = wall + 1376256;
  u16* w5cat = wall + 1638400;  // 256 x 512

  u16* Plb = aggs;  // layer-5 P split lives in the (dead) aggs region
  float* Prf = (float*)((char*)aggs + (size_t)M_PAD * 128 * 2);

  // graph preprocessing
  hipMemsetAsync(deg, 0, (size_t)N_NODES * 4, stream);
  k_deg<<<(N_EDGES + 255) / 256, 256, 0, stream>>>(dstv, deg);
  k_scan1<<<SCAN_NBLK, SCAN_BLK, 0, stream>>>(deg, csr_off, bsum);
  k_scan2_gbounds<<<2, 256, 0, stream>>>(bsum, batch, gstart, inv_sz);
  k_scan3prep<<<SCAN_NBLK, SCAN_BLK, 0, stream>>>(csr_off, bsum, deg, inv_deg, cursor);
  k_scatter<<<(N_EDGES + 255) / 256, 256, 0, stream>>>(srcv, dstv, cursor, csr_src);

  WcSrc ws_src;
  ws_src.p[0] = Wl[0]; ws_src.p[1] = Wr[0];
  ws_src.p[2] = Wl[1]; ws_src.p[3] = Wr[1];
  ws_src.p[4] = Wl[2]; ws_src.p[5] = Wr[2];
  ws_src.p[6] = Wl[3]; ws_src.p[7] = Wr[3];
  ws_src.p[8] = Wl[4]; ws_src.p[9] = Wr[4];
  k_convert_all<<<(XB_EL + WALL_EL + 255) / 256, 256, 0, stream>>>(x, ws_src, xb, wall);

  hipMemsetAsync(stats, 0, (size_t)4 * 2 * N_GROUPS * H_DIM * 4, stream);

  const int nblk_main = M_TILES * 4;  // JB=4
  const int nblk_l5   = M_TILES * 2;  // JB=2

  auto norm = [&](int l) {
    float* ss = stats + (size_t)l * 2 * N_GROUPS * H_DIM;
    float* sq = ss + N_GROUPS * H_DIM;
    k_precomp<<<(N_GROUPS * H_DIM + 255) / 256, 256, 0, stream>>>(
        ss, sq, inv_sz, gamma[l], beta[l], alpha[l], Sbuf, Tbuf);
    k_apply<<<(N_NODES * (H_DIM / 8) + 255) / 256, 256, 0, stream>>>(
        praw, hsA, batch, Sbuf, Tbuf);
  };
  auto stat_ptr = [&](int l) { return stats + (size_t)l * 2 * N_GROUPS * H_DIM; };
  auto agg = [&]() {
    k_agg_slice<<<AGG_BLKS, 256, 0, stream>>>(hsA, csr_off, csr_src, inv_deg, aggs, 0);
    k_agg_slice<<<AGG_BLKS, 256, 0, stream>>>(hsA, csr_off, csr_src, inv_deg, aggs, 1);
  };

  // layer 1 (K = 64 padded, row-major operands)
  k_agg_small<<<N_NODES, 64, 0, stream>>>(xb, csr_off, csr_src, inv_deg, aggx);
  k_gemm_mfma<4, true, 0, false><<<nblk_main, 256, 0, stream>>>(
      aggx, xb, w1lb, w1rb, bb[0], praw, nullptr, batch,
      stat_ptr(0), stat_ptr(0) + N_GROUPS * H_DIM, K1PAD);
  norm(0);

  // layers 2..4: sliced gather (one slice-set per dispatch) + sliced GEMM
  agg();
  k_gemm_mfma<4, true, 0, true><<<nblk_main, 256, 0, stream>>>(
      aggs, hsA, w2lb, w2rb, bb[1], praw, nullptr, batch,
      stat_ptr(1), stat_ptr(1) + N_GROUPS * H_DIM, H_DIM);
  norm(1);

  agg();
  k_gemm_mfma<4, true, 0, true><<<nblk_main, 256, 0, stream>>>(
      aggs, hsA, w3lb, w3rb, bb[2], praw, nullptr, batch,
      stat_ptr(2), stat_ptr(2) + N_GROUPS * H_DIM, H_DIM);
  norm(2);

  agg();
  k_gemm_mfma<4, true, 0, true><<<nblk_main, 256, 0, stream>>>(
      aggs, hsA, w4lb, w4rb, bb[3], praw, nullptr, batch,
      stat_ptr(3), stat_ptr(3) + N_GROUPS * H_DIM, H_DIM);
  norm(3);

  // layer 5 via linearity: P = h @ [W5l|W5r]^T (J=256), then
  // out = inv_deg * segsum(Pl[src]) + Pr + b5
  k_gemm_mfma<2, false, 1, true><<<nblk_l5, 256, 0, stream>>>(
      hsA, nullptr, w5cat, nullptr, nullptr, Plb, Prf, nullptr, nullptr, nullptr, H_DIM);
  k_agg_final<<<(N_NODES + 7) / 8, 256, 0, stream>>>(
      Plb, Prf, csr_off, csr_src, inv_deg, bb[4], (float*)d_out);
}

// Round 8
// 1004.898 us; speedup vs baseline: 1.0741x; 1.0167x over previous
//
#include <hip/hip_runtime.h>
#include <cstddef>
#include <cstdint>

#define N_NODES 50000
#define N_EDGES 800000
#define F_IN 50
#define K1PAD 64
#define H_DIM 512
#define O_DIM 121
#define N_GROUPS 20
#define EPSV 1e-5f
#define M_PAD 50176   // 392 * 128
#define M_TILES 392

#define SCAN_BLK 256
#define SCAN_NBLK ((N_NODES + SCAN_BLK - 1) / SCAN_BLK)  // 196
#define WALL_EL 1769472
#define XB_EL (M_PAD * K1PAD)

typedef unsigned short u16;
typedef __attribute__((ext_vector_type(8))) short short8;          // 8 bf16 (4 VGPRs)
typedef __attribute__((ext_vector_type(8))) unsigned short u16x8;  // 16B vector load
typedef __attribute__((ext_vector_type(4))) float f32x4;

__device__ __forceinline__ float b2f(u16 u) {
  union { unsigned int i; float f; } v; v.i = ((unsigned int)u) << 16; return v.f;
}
__device__ __forceinline__ u16 f2b(float f) {
  union { float f; unsigned int i; } v; v.f = f;
  unsigned int x = v.i;
  return (u16)((x + 0x7fffu + ((x >> 16) & 1u)) >> 16);  // RNE
}

__device__ __forceinline__ void gl_lds16(const void* g, void* l) {
  __builtin_amdgcn_global_load_lds(
      (__attribute__((address_space(1))) void*)(g),
      (__attribute__((address_space(3))) void*)(l), 16, 0, 0);
}

// ---------------- graph preprocessing ----------------

__global__ void k_deg(const int* __restrict__ dst, int* __restrict__ deg) {
  int e = blockIdx.x * blockDim.x + threadIdx.x;
  if (e < N_EDGES) atomicAdd(&deg[dst[e]], 1);
}

__global__ void k_scan1(const int* __restrict__ deg, int* __restrict__ off,
                        int* __restrict__ bsum) {
  __shared__ int buf[SCAN_BLK];
  int gid = blockIdx.x * SCAN_BLK + threadIdx.x;
  buf[threadIdx.x] = (gid < N_NODES) ? deg[gid] : 0;
  __syncthreads();
  for (int d = 1; d < SCAN_BLK; d <<= 1) {
    int t = (threadIdx.x >= d) ? buf[threadIdx.x - d] : 0;
    __syncthreads();
    buf[threadIdx.x] += t;
    __syncthreads();
  }
  if (gid < N_NODES) off[gid + 1] = buf[threadIdx.x];
  if (threadIdx.x == SCAN_BLK - 1) bsum[blockIdx.x] = buf[threadIdx.x];
}

// block 0: scan of block sums; block 1: group bounds from sorted batch
__global__ void k_scan2_gbounds(int* __restrict__ bsum, const int* __restrict__ batch,
                                int* __restrict__ gstart, float* __restrict__ inv_sz) {
  int t = threadIdx.x;
  if (blockIdx.x == 0) {
    __shared__ int buf[256];
    buf[t] = (t < SCAN_NBLK) ? bsum[t] : 0;
    __syncthreads();
    for (int d = 1; d < 256; d <<= 1) {
      int v = (t >= d) ? buf[t - d] : 0;
      __syncthreads();
      buf[t] += v;
      __syncthreads();
    }
    if (t < SCAN_NBLK) bsum[t] = buf[t];
  } else {
    if (t <= N_GROUPS) {
      int lo = 0, hi = N_NODES;
      while (lo < hi) {
        int mid = (lo + hi) >> 1;
        if (batch[mid] < t) lo = mid + 1; else hi = mid;
      }
      gstart[t] = lo;
    }
    __syncthreads();
    if (t < N_GROUPS) {
      int sz = gstart[t + 1] - gstart[t];
      inv_sz[t] = 1.0f / (float)max(sz, 1);
    }
  }
}

__global__ void k_scan3prep(int* __restrict__ off, const int* __restrict__ bsum,
                            const int* __restrict__ deg, float* __restrict__ inv_deg,
                            int* __restrict__ cursor) {
  int gid = blockIdx.x * SCAN_BLK + threadIdx.x;
  if (gid < N_NODES) {
    int add = (blockIdx.x > 0) ? bsum[blockIdx.x - 1] : 0;
    int v = off[gid + 1] + add;
    off[gid + 1] = v;
    if (gid + 1 < N_NODES) cursor[gid + 1] = v;
    inv_deg[gid] = 1.0f / (float)max(deg[gid], 1);
  }
  if (gid == 0) { off[0] = 0; cursor[0] = 0; }
}

__global__ void k_scatter(const int* __restrict__ src, const int* __restrict__ dst,
                          int* __restrict__ cursor, int* __restrict__ csr_src) {
  int e = blockIdx.x * blockDim.x + threadIdx.x;
  if (e < N_EDGES) {
    int p = atomicAdd(&cursor[dst[e]], 1);
    csr_src[p] = src[e];
  }
}

// ---------------- conversions (x pad + all weights, one launch) -------------
struct WcSrc { const float* p[10]; };
__global__ void k_convert_all(const float* __restrict__ x, WcSrc s,
                              u16* __restrict__ xb, u16* __restrict__ wall) {
  int idx = blockIdx.x * blockDim.x + threadIdx.x;
  if (idx < XB_EL) {
    int r = idx >> 6, c = idx & (K1PAD - 1);
    float v = (r < N_NODES && c < F_IN) ? x[r * F_IN + c] : 0.f;
    xb[idx] = f2b(v);
    return;
  }
  idx -= XB_EL;
  if (idx >= WALL_EL) return;
  const int seg_start[10] = {0, 32768, 65536, 327680, 589824, 851968,
                             1114112, 1376256, 1638400, 1703936};
  const int jr[10]  = {512, 512, 512, 512, 512, 512, 512, 512, 121, 121};
  const int kin[10] = {50, 50, 512, 512, 512, 512, 512, 512, 512, 512};
  const int ksh[10] = {6, 6, 9, 9, 9, 9, 9, 9, 9, 9};
  int sgi = 0;
#pragma unroll
  for (int t = 1; t < 10; ++t)
    if (idx >= seg_start[t]) sgi = t;
  int local = idx - seg_start[sgi];
  int j = local >> ksh[sgi];
  int k = local & ((1 << ksh[sgi]) - 1);
  float v = (j < jr[sgi] && k < kin[sgi]) ? s.p[sgi][j * kin[sgi] + k] : 0.f;
  wall[idx] = f2b(v);
}

// ---------------- aggregation ----------------

__global__ void k_agg_small(const u16* __restrict__ xb, const int* __restrict__ off,
                            const int* __restrict__ srcs, const float* __restrict__ inv_deg,
                            u16* __restrict__ agg) {
  int n = blockIdx.x;
  int f = threadIdx.x;  // 0..63
  int b = off[n], e = off[n + 1];
  float s = 0.f;
  for (int i = b; i < e; ++i) s += b2f(xb[(size_t)srcs[i] * K1PAD + f]);
  agg[(size_t)n * K1PAD + f] = f2b(s * inv_deg[n]);
}

// layers 2..4 aggregation, XCD-sliced. h stored SLICED: 16 regions of
// [M_PAD][32] u16 (3.2MB each); slice s = xcd*2+ph processed only by blocks
// on XCD s>>1 (blockIdx&7 -> XCD round-robin).
// ONE PHASE PER DISPATCH (r4: both phases resident -> 2 slices + CSR > 4MB
// L2 -> thrash). NATURAL node order (r3/r6: reordering perms broke CSR/write
// locality). 4-edge unroll EXACTLY (r7: 8-unroll regressed ~+10us/dispatch).
#define AGG_BLKS 2048  // 256 chunks x 8 XCDs
__global__ __launch_bounds__(256) void k_agg_slice(
    const u16* __restrict__ hs, const int* __restrict__ off,
    const int* __restrict__ srcs, const float* __restrict__ inv_deg,
    u16* __restrict__ aggs, int ph) {
  const int xcd = blockIdx.x & 7;
  const int chunk = blockIdx.x >> 3;                 // 0..255
  const int nchunk = AGG_BLKS / 8;                   // 256
  const int per = (N_NODES + nchunk - 1) / nchunk;   // 196
  const int p0 = chunk * per;
  const int p1 = min(p0 + per, N_NODES);
  const int grp = threadIdx.x >> 2;       // 0..63 node-groups per block
  const int sub = (threadIdx.x & 3) * 8;  // u16 offset of this lane's 16B
  const int s = xcd * 2 + ph;
  const u16* hsl = hs + (size_t)s * M_PAD * 32 + sub;
  u16* asl = aggs + (size_t)s * M_PAD * 32 + sub;
  for (int n = p0 + grp; n < p1; n += 64) {
    int b = off[n], e = off[n + 1];
    float a[8] = {};
    int i = b;
    for (; i + 4 <= e; i += 4) {
      u16x8 v0 = *(const u16x8*)(hsl + (size_t)srcs[i + 0] * 32);
      u16x8 v1 = *(const u16x8*)(hsl + (size_t)srcs[i + 1] * 32);
      u16x8 v2 = *(const u16x8*)(hsl + (size_t)srcs[i + 2] * 32);
      u16x8 v3 = *(const u16x8*)(hsl + (size_t)srcs[i + 3] * 32);
#pragma unroll
      for (int j = 0; j < 8; ++j)
        a[j] += (b2f(v0[j]) + b2f(v1[j])) + (b2f(v2[j]) + b2f(v3[j]));
    }
    for (; i < e; ++i) {
      u16x8 v0 = *(const u16x8*)(hsl + (size_t)srcs[i] * 32);
#pragma unroll
      for (int j = 0; j < 8; ++j) a[j] += b2f(v0[j]);
    }
    float w = inv_deg[n];
    u16x8 r;
#pragma unroll
    for (int j = 0; j < 8; ++j) r[j] = f2b(a[j] * w);
    *(u16x8*)(asl + (size_t)n * 32) = r;
  }
}

// layer 5 final: out[n] = inv_deg[n]*sum(Pl[src]) + Pr[n] + bias (121 cols)
__global__ __launch_bounds__(256) void k_agg_final(
    const u16* __restrict__ Plb, const float* __restrict__ Prf,
    const int* __restrict__ off, const int* __restrict__ srcs,
    const float* __restrict__ inv_deg, const float* __restrict__ bias,
    float* __restrict__ out) {
  int n = blockIdx.x * 8 + (threadIdx.x >> 5);
  if (n >= N_NODES) return;
  int l = threadIdx.x & 31;
  int c0 = l * 4;
  int b = off[n], e = off[n + 1];
  float a0 = 0.f, a1 = 0.f, a2 = 0.f, a3 = 0.f;
  int i = b;
  for (; i + 2 <= e; i += 2) {
    ushort4 v0 = ((const ushort4*)(Plb + (size_t)srcs[i] * 128))[l];
    ushort4 v1 = ((const ushort4*)(Plb + (size_t)srcs[i + 1] * 128))[l];
    a0 += b2f(v0.x) + b2f(v1.x); a1 += b2f(v0.y) + b2f(v1.y);
    a2 += b2f(v0.z) + b2f(v1.z); a3 += b2f(v0.w) + b2f(v1.w);
  }
  if (i < e) {
    ushort4 v0 = ((const ushort4*)(Plb + (size_t)srcs[i] * 128))[l];
    a0 += b2f(v0.x); a1 += b2f(v0.y); a2 += b2f(v0.z); a3 += b2f(v0.w);
  }
  float w = inv_deg[n];
  float4 pr = ((const float4*)(Prf + (size_t)n * 128))[l];
  float r0 = a0 * w + pr.x, r1 = a1 * w + pr.y;
  float r2 = a2 * w + pr.z, r3 = a3 * w + pr.w;
  size_t ob = (size_t)n * O_DIM;
  if (c0 + 0 < O_DIM) out[ob + c0 + 0] = r0 + bias[c0 + 0];
  if (c0 + 1 < O_DIM) out[ob + c0 + 1] = r1 + bias[c0 + 1];
  if (c0 + 2 < O_DIM) out[ob + c0 + 2] = r2 + bias[c0 + 2];
  if (c0 + 3 < O_DIM) out[ob + c0 + 3] = r3 + bias[c0 + 3];
}

// ---------------- MFMA GEMM ----------------
// DUAL(OUTMODE 0): C = A*Wl^T + X*Wr^T + b, bf16 out [*, 512]; GraphNorm
//   stats fused in epilogue. !DUAL(OUTMODE 1): P = A*Wl^T split bf16/f32.
// SL: A/X in the 16x[M_PAD][32] sliced layout.
// K-loop: simple 2-barrier form (r6: counted-vmcnt pipeline regressed via
//   occupancy). EPILOGUE (r7-verified WIN: WRITE 83->57.6MB, dur 98->86):
//   stage the wave's 64x64 bf16 tile into its dead 8KB of staging LDS,
//   XOR-swizzled, then store 8 coalesced 16B/lane full-128B-segment stores.

#define TM 128
#define TK 32

template <int JB, bool DUAL, int OUTMODE, bool SL>
__global__ __launch_bounds__(256, 4) void k_gemm_mfma(
    const u16* __restrict__ A, const u16* __restrict__ X,
    const u16* __restrict__ Wl, const u16* __restrict__ Wr,
    const float* __restrict__ bias, void* __restrict__ C0,
    void* __restrict__ C1, const int* __restrict__ batch,
    float* __restrict__ ssum, float* __restrict__ ssq, int K) {
  __shared__ u16 smem[DUAL ? 16384 : 8192];
  u16* As = smem;
  u16* Ls = smem + 4096;
  u16* Xs = DUAL ? smem + 8192 : smem;
  u16* Rs = DUAL ? smem + 12288 : smem;

  int id = blockIdx.x;
  const int nfull = (M_TILES >> 3) * 8 * JB;
  int m_t, j_t;
  if (id < nfull) {
    m_t = (id / (8 * JB)) * 8 + (id & 7);
    j_t = (id >> 3) & (JB - 1);
  } else {
    int rem = id - nfull;
    const int nrem = (M_TILES & 7) ? (M_TILES & 7) : 1;
    m_t = (M_TILES & ~7) + rem % nrem;
    j_t = rem / nrem;
  }
  int m0 = m_t * TM;
  int j0 = j_t * 128;

  int tid = threadIdx.x;
  int lane = tid & 63;
  int wave = tid >> 6;
  int quad = lane >> 4;
  int lr = lane & 15;
  int wm = (wave & 1) * 64;
  int wn = (wave >> 1) * 64;

  f32x4 acc[4][4] = {};

  int sr = tid >> 2;
  int sc = (tid & 3) * 8;
  const size_t kstep = SL ? (size_t)M_PAD * 32 : (size_t)TK;
  const size_t rstep = SL ? (size_t)64 * 32 : (size_t)64 * K;
  const u16* Ap = A + (SL ? (size_t)(m0 + sr) * 32 + sc
                          : (size_t)(m0 + sr) * K + sc);
  const u16* Xp = nullptr;
  if constexpr (DUAL)
    Xp = X + (SL ? (size_t)(m0 + sr) * 32 + sc
                 : (size_t)(m0 + sr) * K + sc);
  size_t joff0 = (size_t)(j0 + sr) * K + sc;
  size_t joff1 = joff0 + (size_t)64 * K;
  const int dofs = tid * 8;

  for (int k0 = 0; k0 < K; k0 += TK) {
    __syncthreads();
    gl_lds16(Ap, As + dofs);
    gl_lds16(Ap + rstep, As + 2048 + dofs);
    gl_lds16(Wl + joff0 + k0, Ls + dofs);
    gl_lds16(Wl + joff1 + k0, Ls + 2048 + dofs);
    if constexpr (DUAL) {
      gl_lds16(Xp, Xs + dofs);
      gl_lds16(Xp + rstep, Xs + 2048 + dofs);
      gl_lds16(Wr + joff0 + k0, Rs + dofs);
      gl_lds16(Wr + joff1 + k0, Rs + 2048 + dofs);
      Xp += kstep;
    }
    Ap += kstep;
    __syncthreads();
    {
      short8 af[4], lf[4];
#pragma unroll
      for (int t = 0; t < 4; ++t) {
        af[t] = *(const short8*)(As + (wm + t * 16 + lr) * TK + quad * 8);
        lf[t] = *(const short8*)(Ls + (wn + t * 16 + lr) * TK + quad * 8);
      }
#pragma unroll
      for (int ti = 0; ti < 4; ++ti)
#pragma unroll
        for (int tj = 0; tj < 4; ++tj)
          acc[ti][tj] = __builtin_amdgcn_mfma_f32_16x16x32_bf16(
              af[ti], lf[tj], acc[ti][tj], 0, 0, 0);
    }
    if constexpr (DUAL) {
      short8 xf[4], rf[4];
#pragma unroll
      for (int t = 0; t < 4; ++t) {
        xf[t] = *(const short8*)(Xs + (wm + t * 16 + lr) * TK + quad * 8);
        rf[t] = *(const short8*)(Rs + (wn + t * 16 + lr) * TK + quad * 8);
      }
#pragma unroll
      for (int ti = 0; ti < 4; ++ti)
#pragma unroll
        for (int tj = 0; tj < 4; ++tj)
          acc[ti][tj] = __builtin_amdgcn_mfma_f32_16x16x32_bf16(
              xf[ti], rf[tj], acc[ti][tj], 0, 0, 0);
    }
  }

  // epilogue: C/D layout col=lane&15, row=quad*4+reg (m89-verified)
  if constexpr (OUTMODE == 0) {
    __syncthreads();  // all waves done with staging LDS reads -> reuse as wbuf
    u16* wbuf = smem + wave * 4096;  // wave-private 64x64 u16, XOR-swizzled
    int glo = batch[m0];
    int lastrow = m0 + TM - 1;
    bool fast = (lastrow < N_NODES) && (batch[lastrow] == glo);
#pragma unroll
    for (int tj = 0; tj < 4; ++tj) {
      int gcol = j0 + wn + tj * 16 + lr;
      int cl = tj * 16 + lr;  // local col
      float bv = bias[gcol];
      float s = 0.f, q = 0.f;
#pragma unroll
      for (int ti = 0; ti < 4; ++ti) {
        f32x4 v = acc[ti][tj];
        int rbase = m0 + wm + ti * 16 + quad * 4;
        int rl0 = ti * 16 + quad * 4;  // local row base
        if (fast) {
#pragma unroll
          for (int r = 0; r < 4; ++r) {
            float val = v[r] + bv;
            int rl = rl0 + r;
            int bo = (rl * 128 + cl * 2) ^ (((rl >> 2) & 3) << 5);
            *(u16*)((char*)wbuf + bo) = f2b(val);
            s += val; q += val * val;
          }
        } else {
          if (rbase + 3 < N_NODES && batch[rbase] == batch[rbase + 3]) {
            float s4 = 0.f, q4 = 0.f;
#pragma unroll
            for (int r = 0; r < 4; ++r) {
              float val = v[r] + bv;
              int rl = rl0 + r;
              int bo = (rl * 128 + cl * 2) ^ (((rl >> 2) & 3) << 5);
              *(u16*)((char*)wbuf + bo) = f2b(val);
              s4 += val; q4 += val * val;
            }
            int g = batch[rbase];
            atomicAdd(&ssum[g * H_DIM + gcol], s4);
            atomicAdd(&ssq[g * H_DIM + gcol], q4);
          } else {
#pragma unroll
            for (int r = 0; r < 4; ++r) {
              int grow = rbase + r;
              float val = v[r] + bv;
              int rl = rl0 + r;
              int bo = (rl * 128 + cl * 2) ^ (((rl >> 2) & 3) << 5);
              *(u16*)((char*)wbuf + bo) = f2b(val);  // padding rows land in praw pad
              if (grow < N_NODES) {
                int g = batch[grow];
                atomicAdd(&ssum[g * H_DIM + gcol], val);
                atomicAdd(&ssq[g * H_DIM + gcol], val * val);
              }
            }
          }
        }
      }
      if (fast) {
        s += __shfl_xor(s, 16); s += __shfl_xor(s, 32);
        q += __shfl_xor(q, 16); q += __shfl_xor(q, 32);
        if (quad == 0) {
          atomicAdd(&ssum[glo * H_DIM + gcol], s);
          atomicAdd(&ssq[glo * H_DIM + gcol], q);
        }
      }
    }
    __syncthreads();  // wave's LDS writes complete before read-back
#pragma unroll
    for (int it = 0; it < 8; ++it) {
      int rl = it * 8 + (lane >> 3);
      int c0 = (lane & 7) * 8;
      int bo = (rl * 128 + c0 * 2) ^ (((rl >> 2) & 3) << 5);
      u16x8 vv = *(const u16x8*)((const char*)wbuf + bo);
      *(u16x8*)((u16*)C0 + (size_t)(m0 + wm + rl) * H_DIM + (j0 + wn + c0)) = vv;
    }
  } else {
#pragma unroll
    for (int tj = 0; tj < 4; ++tj) {
      int gcol = j0 + wn + tj * 16 + lr;
#pragma unroll
      for (int ti = 0; ti < 4; ++ti) {
        f32x4 v = acc[ti][tj];
#pragma unroll
        for (int r = 0; r < 4; ++r) {
          int grow = m0 + wm + ti * 16 + quad * 4 + r;
          if (gcol < 128)
            ((u16*)C0)[(size_t)grow * 128 + gcol] = f2b(v[r]);
          else
            ((float*)C1)[(size_t)grow * 128 + (gcol - 128)] = v[r];
        }
      }
    }
  }
}

// ---------------- GraphNorm: precompute affine, then apply+relu -------------

__global__ void k_precomp(const float* __restrict__ ssum, const float* __restrict__ ssq,
                          const float* __restrict__ inv_sz, const float* __restrict__ gw,
                          const float* __restrict__ gb, const float* __restrict__ alpha,
                          float* __restrict__ S, float* __restrict__ T) {
  int idx = blockIdx.x * blockDim.x + threadIdx.x;
  if (idx >= N_GROUPS * H_DIM) return;
  int g = idx >> 9;
  int c = idx & (H_DIM - 1);
  float is = inv_sz[g];
  float m = ssum[idx] * is;
  float a = alpha[c];
  float var = fmaxf(ssq[idx] * is - a * (2.f - a) * m * m, 0.f);
  float inv = rsqrtf(var + EPSV);
  float sc = inv * gw[c];
  S[idx] = sc;
  T[idx] = gb[c] - a * m * sc;
}

// reads row-major pre-norm GEMM output, writes normalized+relu'd h in the
// SLICED layout (16 x [M_PAD][32] u16 contiguous slices).
__global__ void k_apply(const u16* __restrict__ praw, u16* __restrict__ hs,
                        const int* __restrict__ batch,
                        const float* __restrict__ S, const float* __restrict__ T) {
  int tid = blockIdx.x * blockDim.x + threadIdx.x;
  if (tid >= N_NODES * (H_DIM / 8)) return;
  int n = tid >> 6;
  int c0 = (tid & 63) << 3;
  int g = batch[n];
  u16x8 hv = *(const u16x8*)(praw + (size_t)n * H_DIM + c0);
  u16x8 out;
#pragma unroll
  for (int j = 0; j < 8; ++j) {
    int f = c0 + j;
    float y = b2f(hv[j]) * S[g * H_DIM + f] + T[g * H_DIM + f];
    out[j] = f2b(fmaxf(y, 0.f));
  }
  *(u16x8*)(hs + ((size_t)(c0 >> 5) * M_PAD + n) * 32 + (c0 & 31)) = out;
}

// ---------------- driver ----------------

extern "C" void kernel_launch(void* const* d_in, const int* in_sizes, int n_in,
                              void* d_out, int out_size, void* d_ws, size_t ws_size,
                              hipStream_t stream) {
  const float* x = (const float*)d_in[0];
  const int* edge = (const int*)d_in[1];
  const int* batch = (const int*)d_in[2];
  const float *Wl[5], *Wr[5], *bb[5];
  for (int i = 0; i < 5; ++i) {
    Wl[i] = (const float*)d_in[3 + 3 * i];
    Wr[i] = (const float*)d_in[4 + 3 * i];
    bb[i] = (const float*)d_in[5 + 3 * i];
  }
  const float *gamma[4], *beta[4], *alpha[4];
  for (int i = 0; i < 4; ++i) {
    gamma[i] = (const float*)d_in[18 + 3 * i];
    beta[i]  = (const float*)d_in[19 + 3 * i];
    alpha[i] = (const float*)d_in[20 + 3 * i];
  }
  const int* srcv = edge;
  const int* dstv = edge + N_EDGES;

  char* base = (char*)d_ws;
  size_t off = 0;
  auto carve = [&](size_t bytes) -> char* {
    char* p = base + off;
    off = (off + bytes + 255) & ~(size_t)255;
    return p;
  };
  int* deg       = (int*)carve((size_t)N_NODES * 4);
  float* inv_deg = (float*)carve((size_t)N_NODES * 4);
  int* csr_off   = (int*)carve((size_t)(N_NODES + 1) * 4);
  int* cursor    = (int*)carve((size_t)N_NODES * 4);
  int* csr_src   = (int*)carve((size_t)N_EDGES * 4);
  int* bsum      = (int*)carve((size_t)SCAN_NBLK * 4);
  int* gstart    = (int*)carve((size_t)(N_GROUPS + 1) * 4);
  float* inv_sz  = (float*)carve((size_t)N_GROUPS * 4);
  float* stats   = (float*)carve((size_t)4 * 2 * N_GROUPS * H_DIM * 4);
  float* Sbuf    = (float*)carve((size_t)N_GROUPS * H_DIM * 4);
  float* Tbuf    = (float*)carve((size_t)N_GROUPS * H_DIM * 4);
  u16* xb        = (u16*)carve((size_t)XB_EL * 2);
  u16* aggx      = (u16*)carve((size_t)XB_EL * 2);
  u16* praw      = (u16*)carve((size_t)M_PAD * H_DIM * 2);  // pre-norm GEMM out (rm)
  u16* hsA       = (u16*)carve((size_t)M_PAD * H_DIM * 2);  // normalized h (sliced)
  u16* aggs      = (u16*)carve((size_t)M_PAD * H_DIM * 2);  // aggregated h (sliced)
  u16* wall      = (u16*)carve((size_t)WALL_EL * 2);
  (void)ws_size; (void)in_sizes; (void)n_in; (void)out_size;

  u16* w1lb = wall;
  u16* w1rb = wall + 32768;
  u16* w2lb = wall + 65536;
  u16* w2rb = wall + 327680;
  u16* w3lb = wall + 589824;
  u16* w3rb = wall + 851968;
  u16* w4lb = wall + 1114112;
  u16* w4rb = wall + 1376256;
  u16* w5cat = wall + 1638400;  // 256 x 512

  u16* Plb = aggs;  // layer-5 P split lives in the (dead) aggs region
  float* Prf = (float*)((char*)aggs + (size_t)M_PAD * 128 * 2);

  // graph preprocessing
  hipMemsetAsync(deg, 0, (size_t)N_NODES * 4, stream);
  k_deg<<<(N_EDGES + 255) / 256, 256, 0, stream>>>(dstv, deg);
  k_scan1<<<SCAN_NBLK, SCAN_BLK, 0, stream>>>(deg, csr_off, bsum);
  k_scan2_gbounds<<<2, 256, 0, stream>>>(bsum, batch, gstart, inv_sz);
  k_scan3prep<<<SCAN_NBLK, SCAN_BLK, 0, stream>>>(csr_off, bsum, deg, inv_deg, cursor);
  k_scatter<<<(N_EDGES + 255) / 256, 256, 0, stream>>>(srcv, dstv, cursor, csr_src);

  WcSrc ws_src;
  ws_src.p[0] = Wl[0]; ws_src.p[1] = Wr[0];
  ws_src.p[2] = Wl[1]; ws_src.p[3] = Wr[1];
  ws_src.p[4] = Wl[2]; ws_src.p[5] = Wr[2];
  ws_src.p[6] = Wl[3]; ws_src.p[7] = Wr[3];
  ws_src.p[8] = Wl[4]; ws_src.p[9] = Wr[4];
  k_convert_all<<<(XB_EL + WALL_EL + 255) / 256, 256, 0, stream>>>(x, ws_src, xb, wall);

  hipMemsetAsync(stats, 0, (size_t)4 * 2 * N_GROUPS * H_DIM * 4, stream);

  const int nblk_main = M_TILES * 4;  // JB=4
  const int nblk_l5   = M_TILES * 2;  // JB=2

  auto norm = [&](int l) {
    float* ss = stats + (size_t)l * 2 * N_GROUPS * H_DIM;
    float* sq = ss + N_GROUPS * H_DIM;
    k_precomp<<<(N_GROUPS * H_DIM + 255) / 256, 256, 0, stream>>>(
        ss, sq, inv_sz, gamma[l], beta[l], alpha[l], Sbuf, Tbuf);
    k_apply<<<(N_NODES * (H_DIM / 8) + 255) / 256, 256, 0, stream>>>(
        praw, hsA, batch, Sbuf, Tbuf);
  };
  auto stat_ptr = [&](int l) { return stats + (size_t)l * 2 * N_GROUPS * H_DIM; };
  auto agg = [&]() {
    k_agg_slice<<<AGG_BLKS, 256, 0, stream>>>(hsA, csr_off, csr_src, inv_deg, aggs, 0);
    k_agg_slice<<<AGG_BLKS, 256, 0, stream>>>(hsA, csr_off, csr_src, inv_deg, aggs, 1);
  };

  // layer 1 (K = 64 padded, row-major operands)
  k_agg_small<<<N_NODES, 64, 0, stream>>>(xb, csr_off, csr_src, inv_deg, aggx);
  k_gemm_mfma<4, true, 0, false><<<nblk_main, 256, 0, stream>>>(
      aggx, xb, w1lb, w1rb, bb[0], praw, nullptr, batch,
      stat_ptr(0), stat_ptr(0) + N_GROUPS * H_DIM, K1PAD);
  norm(0);

  // layers 2..4: sliced gather (one slice-set per dispatch) + sliced GEMM
  agg();
  k_gemm_mfma<4, true, 0, true><<<nblk_main, 256, 0, stream>>>(
      aggs, hsA, w2lb, w2rb, bb[1], praw, nullptr, batch,
      stat_ptr(1), stat_ptr(1) + N_GROUPS * H_DIM, H_DIM);
  norm(1);

  agg();
  k_gemm_mfma<4, true, 0, true><<<nblk_main, 256, 0, stream>>>(
      aggs, hsA, w3lb, w3rb, bb[2], praw, nullptr, batch,
      stat_ptr(2), stat_ptr(2) + N_GROUPS * H_DIM, H_DIM);
  norm(2);

  agg();
  k_gemm_mfma<4, true, 0, true><<<nblk_main, 256, 0, stream>>>(
      aggs, hsA, w4lb, w4rb, bb[3], praw, nullptr, batch,
      stat_ptr(3), stat_ptr(3) + N_GROUPS * H_DIM, H_DIM);
  norm(3);

  // layer 5 via linearity: P = h @ [W5l|W5r]^T (J=256), then
  // out = inv_deg * segsum(Pl[src]) + Pr + b5
  k_gemm_mfma<2, false, 1, true><<<nblk_l5, 256, 0, stream>>>(
      hsA, nullptr, w5cat, nullptr, nullptr, Plb, Prf, nullptr, nullptr, nullptr, H_DIM);
  k_agg_final<<<(N_NODES + 7) / 8, 256, 0, stream>>>(
      Plb, Prf, csr_off, csr_src, inv_deg, bb[4], (float*)d_out);
}

// Round 9
// 1003.738 us; speedup vs baseline: 1.0753x; 1.0012x over previous
//
#include <hip/hip_runtime.h>
#include <cstddef>
#include <cstdint>

#define N_NODES 50000
#define N_EDGES 800000
#define F_IN 50
#define K1PAD 64
#define H_DIM 512
#define O_DIM 121
#define N_GROUPS 20
#define EPSV 1e-5f
#define M_PAD 50176   // 392 * 128
#define M_TILES 392

#define SCAN_BLK 256
#define SCAN_NBLK ((N_NODES + SCAN_BLK - 1) / SCAN_BLK)  // 196
#define WALL_EL 1769472
#define XB_EL (M_PAD * K1PAD)

typedef unsigned short u16;
typedef __attribute__((ext_vector_type(8))) short short8;          // 8 bf16 (4 VGPRs)
typedef __attribute__((ext_vector_type(8))) unsigned short u16x8;  // 16B vector load
typedef __attribute__((ext_vector_type(4))) float f32x4;
typedef __attribute__((ext_vector_type(2))) float f32x2;

__device__ __forceinline__ float b2f(u16 u) {
  union { unsigned int i; float f; } v; v.i = ((unsigned int)u) << 16; return v.f;
}
__device__ __forceinline__ u16 f2b(float f) {
  union { float f; unsigned int i; } v; v.f = f;
  unsigned int x = v.i;
  return (u16)((x + 0x7fffu + ((x >> 16) & 1u)) >> 16);  // RNE
}

// unpack one dword (2 bf16) to f32x2 {lo, hi}: 2 VALU + downstream pk-adds
__device__ __forceinline__ f32x2 up2(unsigned int d) {
  union { unsigned int u; float f; } lo, hi;
  lo.u = d << 16;
  hi.u = d & 0xffff0000u;
  f32x2 r; r.x = lo.f; r.y = hi.f;
  return r;
}

__device__ __forceinline__ void gl_lds16(const void* g, void* l) {
  __builtin_amdgcn_global_load_lds(
      (__attribute__((address_space(1))) void*)(g),
      (__attribute__((address_space(3))) void*)(l), 16, 0, 0);
}

// ---------------- graph preprocessing ----------------

__global__ void k_deg(const int* __restrict__ dst, int* __restrict__ deg) {
  int e = blockIdx.x * blockDim.x + threadIdx.x;
  if (e < N_EDGES) atomicAdd(&deg[dst[e]], 1);
}

__global__ void k_scan1(const int* __restrict__ deg, int* __restrict__ off,
                        int* __restrict__ bsum) {
  __shared__ int buf[SCAN_BLK];
  int gid = blockIdx.x * SCAN_BLK + threadIdx.x;
  buf[threadIdx.x] = (gid < N_NODES) ? deg[gid] : 0;
  __syncthreads();
  for (int d = 1; d < SCAN_BLK; d <<= 1) {
    int t = (threadIdx.x >= d) ? buf[threadIdx.x - d] : 0;
    __syncthreads();
    buf[threadIdx.x] += t;
    __syncthreads();
  }
  if (gid < N_NODES) off[gid + 1] = buf[threadIdx.x];
  if (threadIdx.x == SCAN_BLK - 1) bsum[blockIdx.x] = buf[threadIdx.x];
}

// block 0: scan of block sums; block 1: group bounds from sorted batch
__global__ void k_scan2_gbounds(int* __restrict__ bsum, const int* __restrict__ batch,
                                int* __restrict__ gstart, float* __restrict__ inv_sz) {
  int t = threadIdx.x;
  if (blockIdx.x == 0) {
    __shared__ int buf[256];
    buf[t] = (t < SCAN_NBLK) ? bsum[t] : 0;
    __syncthreads();
    for (int d = 1; d < 256; d <<= 1) {
      int v = (t >= d) ? buf[t - d] : 0;
      __syncthreads();
      buf[t] += v;
      __syncthreads();
    }
    if (t < SCAN_NBLK) bsum[t] = buf[t];
  } else {
    if (t <= N_GROUPS) {
      int lo = 0, hi = N_NODES;
      while (lo < hi) {
        int mid = (lo + hi) >> 1;
        if (batch[mid] < t) lo = mid + 1; else hi = mid;
      }
      gstart[t] = lo;
    }
    __syncthreads();
    if (t < N_GROUPS) {
      int sz = gstart[t + 1] - gstart[t];
      inv_sz[t] = 1.0f / (float)max(sz, 1);
    }
  }
}

__global__ void k_scan3prep(int* __restrict__ off, const int* __restrict__ bsum,
                            const int* __restrict__ deg, float* __restrict__ inv_deg,
                            int* __restrict__ cursor) {
  int gid = blockIdx.x * SCAN_BLK + threadIdx.x;
  if (gid < N_NODES) {
    int add = (blockIdx.x > 0) ? bsum[blockIdx.x - 1] : 0;
    int v = off[gid + 1] + add;
    off[gid + 1] = v;
    if (gid + 1 < N_NODES) cursor[gid + 1] = v;
    inv_deg[gid] = 1.0f / (float)max(deg[gid], 1);
  }
  if (gid == 0) { off[0] = 0; cursor[0] = 0; }
}

__global__ void k_scatter(const int* __restrict__ src, const int* __restrict__ dst,
                          int* __restrict__ cursor, int* __restrict__ csr_src) {
  int e = blockIdx.x * blockDim.x + threadIdx.x;
  if (e < N_EDGES) {
    int p = atomicAdd(&cursor[dst[e]], 1);
    csr_src[p] = src[e];
  }
}

// ---------------- conversions (x pad + all weights, one launch) -------------
struct WcSrc { const float* p[10]; };
__global__ void k_convert_all(const float* __restrict__ x, WcSrc s,
                              u16* __restrict__ xb, u16* __restrict__ wall) {
  int idx = blockIdx.x * blockDim.x + threadIdx.x;
  if (idx < XB_EL) {
    int r = idx >> 6, c = idx & (K1PAD - 1);
    float v = (r < N_NODES && c < F_IN) ? x[r * F_IN + c] : 0.f;
    xb[idx] = f2b(v);
    return;
  }
  idx -= XB_EL;
  if (idx >= WALL_EL) return;
  const int seg_start[10] = {0, 32768, 65536, 327680, 589824, 851968,
                             1114112, 1376256, 1638400, 1703936};
  const int jr[10]  = {512, 512, 512, 512, 512, 512, 512, 512, 121, 121};
  const int kin[10] = {50, 50, 512, 512, 512, 512, 512, 512, 512, 512};
  const int ksh[10] = {6, 6, 9, 9, 9, 9, 9, 9, 9, 9};
  int sgi = 0;
#pragma unroll
  for (int t = 1; t < 10; ++t)
    if (idx >= seg_start[t]) sgi = t;
  int local = idx - seg_start[sgi];
  int j = local >> ksh[sgi];
  int k = local & ((1 << ksh[sgi]) - 1);
  float v = (j < jr[sgi] && k < kin[sgi]) ? s.p[sgi][j * kin[sgi] + k] : 0.f;
  wall[idx] = f2b(v);
}

// ---------------- aggregation ----------------

__global__ void k_agg_small(const u16* __restrict__ xb, const int* __restrict__ off,
                            const int* __restrict__ srcs, const float* __restrict__ inv_deg,
                            u16* __restrict__ agg) {
  int n = blockIdx.x;
  int f = threadIdx.x;  // 0..63
  int b = off[n], e = off[n + 1];
  float s = 0.f;
  for (int i = b; i < e; ++i) s += b2f(xb[(size_t)srcs[i] * K1PAD + f]);
  agg[(size_t)n * K1PAD + f] = f2b(s * inv_deg[n]);
}

// layers 2..4 aggregation, XCD-sliced. h stored SLICED: 16 regions of
// [M_PAD][32] u16 (3.2MB each); slice s = xcd*2+ph processed only by blocks
// on XCD s>>1 (blockIdx&7 -> XCD round-robin).
// ONE PHASE PER DISPATCH (r4: both phases resident -> 2 slices + CSR > 4MB
// L2 -> thrash). NATURAL node order (r3/r6: reordering perms broke CSR/write
// locality). 4-edge unroll EXACTLY (r7: 8-unroll regressed).
// r9: accumulate as f32x2 (v_pk_add_f32) with dword-wise bf16 unpack --
// ~25% fewer VALU insts, bit-identical per-channel summation order.
#define AGG_BLKS 2048  // 256 chunks x 8 XCDs
__global__ __launch_bounds__(256) void k_agg_slice(
    const u16* __restrict__ hs, const int* __restrict__ off,
    const int* __restrict__ srcs, const float* __restrict__ inv_deg,
    u16* __restrict__ aggs, int ph) {
  const int xcd = blockIdx.x & 7;
  const int chunk = blockIdx.x >> 3;                 // 0..255
  const int nchunk = AGG_BLKS / 8;                   // 256
  const int per = (N_NODES + nchunk - 1) / nchunk;   // 196
  const int p0 = chunk * per;
  const int p1 = min(p0 + per, N_NODES);
  const int grp = threadIdx.x >> 2;       // 0..63 node-groups per block
  const int sub = (threadIdx.x & 3) * 8;  // u16 offset of this lane's 16B
  const int s = xcd * 2 + ph;
  const u16* hsl = hs + (size_t)s * M_PAD * 32 + sub;
  u16* asl = aggs + (size_t)s * M_PAD * 32 + sub;
  for (int n = p0 + grp; n < p1; n += 64) {
    int b = off[n], e = off[n + 1];
    f32x2 a0 = {0.f, 0.f}, a1 = {0.f, 0.f}, a2 = {0.f, 0.f}, a3 = {0.f, 0.f};
    int i = b;
    for (; i + 4 <= e; i += 4) {
      uint4 w0 = *(const uint4*)(hsl + (size_t)srcs[i + 0] * 32);
      uint4 w1 = *(const uint4*)(hsl + (size_t)srcs[i + 1] * 32);
      uint4 w2 = *(const uint4*)(hsl + (size_t)srcs[i + 2] * 32);
      uint4 w3 = *(const uint4*)(hsl + (size_t)srcs[i + 3] * 32);
      a0 += (up2(w0.x) + up2(w1.x)) + (up2(w2.x) + up2(w3.x));
      a1 += (up2(w0.y) + up2(w1.y)) + (up2(w2.y) + up2(w3.y));
      a2 += (up2(w0.z) + up2(w1.z)) + (up2(w2.z) + up2(w3.z));
      a3 += (up2(w0.w) + up2(w1.w)) + (up2(w2.w) + up2(w3.w));
    }
    for (; i < e; ++i) {
      uint4 w0 = *(const uint4*)(hsl + (size_t)srcs[i] * 32);
      a0 += up2(w0.x); a1 += up2(w0.y); a2 += up2(w0.z); a3 += up2(w0.w);
    }
    float iw = inv_deg[n];
    u16x8 r;
    r[0] = f2b(a0.x * iw); r[1] = f2b(a0.y * iw);
    r[2] = f2b(a1.x * iw); r[3] = f2b(a1.y * iw);
    r[4] = f2b(a2.x * iw); r[5] = f2b(a2.y * iw);
    r[6] = f2b(a3.x * iw); r[7] = f2b(a3.y * iw);
    *(u16x8*)(asl + (size_t)n * 32) = r;
  }
}

// layer 5 final: out[n] = inv_deg[n]*sum(Pl[src]) + Pr[n] + bias (121 cols)
__global__ __launch_bounds__(256) void k_agg_final(
    const u16* __restrict__ Plb, const float* __restrict__ Prf,
    const int* __restrict__ off, const int* __restrict__ srcs,
    const float* __restrict__ inv_deg, const float* __restrict__ bias,
    float* __restrict__ out) {
  int n = blockIdx.x * 8 + (threadIdx.x >> 5);
  if (n >= N_NODES) return;
  int l = threadIdx.x & 31;
  int c0 = l * 4;
  int b = off[n], e = off[n + 1];
  float a0 = 0.f, a1 = 0.f, a2 = 0.f, a3 = 0.f;
  int i = b;
  for (; i + 2 <= e; i += 2) {
    ushort4 v0 = ((const ushort4*)(Plb + (size_t)srcs[i] * 128))[l];
    ushort4 v1 = ((const ushort4*)(Plb + (size_t)srcs[i + 1] * 128))[l];
    a0 += b2f(v0.x) + b2f(v1.x); a1 += b2f(v0.y) + b2f(v1.y);
    a2 += b2f(v0.z) + b2f(v1.z); a3 += b2f(v0.w) + b2f(v1.w);
  }
  if (i < e) {
    ushort4 v0 = ((const ushort4*)(Plb + (size_t)srcs[i] * 128))[l];
    a0 += b2f(v0.x); a1 += b2f(v0.y); a2 += b2f(v0.z); a3 += b2f(v0.w);
  }
  float w = inv_deg[n];
  float4 pr = ((const float4*)(Prf + (size_t)n * 128))[l];
  float r0 = a0 * w + pr.x, r1 = a1 * w + pr.y;
  float r2 = a2 * w + pr.z, r3 = a3 * w + pr.w;
  size_t ob = (size_t)n * O_DIM;
  if (c0 + 0 < O_DIM) out[ob + c0 + 0] = r0 + bias[c0 + 0];
  if (c0 + 1 < O_DIM) out[ob + c0 + 1] = r1 + bias[c0 + 1];
  if (c0 + 2 < O_DIM) out[ob + c0 + 2] = r2 + bias[c0 + 2];
  if (c0 + 3 < O_DIM) out[ob + c0 + 3] = r3 + bias[c0 + 3];
}

// ---------------- MFMA GEMM ----------------
// DUAL(OUTMODE 0): C = A*Wl^T + X*Wr^T + b, bf16 out [*, 512]; GraphNorm
//   stats fused in epilogue. !DUAL(OUTMODE 1): P = A*Wl^T split bf16/f32.
// SL: A/X in the 16x[M_PAD][32] sliced layout.
// K-loop: simple 2-barrier form (r6: counted-vmcnt pipeline regressed via
//   occupancy). EPILOGUE (r7-verified WIN on OUTMODE 0: WRITE 83->57.6MB,
//   dur 98->86): stage the wave's 64x64 bf16 tile into its dead staging
//   LDS, XOR-swizzled, then 8 coalesced full-128B-segment stores.
//   r9: same treatment for OUTMODE 1's u16 half (blocks split cleanly:
//   j0==0 all-u16, j0==128 all-f32).

#define TM 128
#define TK 32

template <int JB, bool DUAL, int OUTMODE, bool SL>
__global__ __launch_bounds__(256, 4) void k_gemm_mfma(
    const u16* __restrict__ A, const u16* __restrict__ X,
    const u16* __restrict__ Wl, const u16* __restrict__ Wr,
    const float* __restrict__ bias, void* __restrict__ C0,
    void* __restrict__ C1, const int* __restrict__ batch,
    float* __restrict__ ssum, float* __restrict__ ssq, int K) {
  __shared__ u16 smem[(DUAL || OUTMODE == 1) ? 16384 : 8192];
  u16* As = smem;
  u16* Ls = smem + 4096;
  u16* Xs = DUAL ? smem + 8192 : smem;
  u16* Rs = DUAL ? smem + 12288 : smem;

  int id = blockIdx.x;
  const int nfull = (M_TILES >> 3) * 8 * JB;
  int m_t, j_t;
  if (id < nfull) {
    m_t = (id / (8 * JB)) * 8 + (id & 7);
    j_t = (id >> 3) & (JB - 1);
  } else {
    int rem = id - nfull;
    const int nrem = (M_TILES & 7) ? (M_TILES & 7) : 1;
    m_t = (M_TILES & ~7) + rem % nrem;
    j_t = rem / nrem;
  }
  int m0 = m_t * TM;
  int j0 = j_t * 128;

  int tid = threadIdx.x;
  int lane = tid & 63;
  int wave = tid >> 6;
  int quad = lane >> 4;
  int lr = lane & 15;
  int wm = (wave & 1) * 64;
  int wn = (wave >> 1) * 64;

  f32x4 acc[4][4] = {};

  int sr = tid >> 2;
  int sc = (tid & 3) * 8;
  const size_t kstep = SL ? (size_t)M_PAD * 32 : (size_t)TK;
  const size_t rstep = SL ? (size_t)64 * 32 : (size_t)64 * K;
  const u16* Ap = A + (SL ? (size_t)(m0 + sr) * 32 + sc
                          : (size_t)(m0 + sr) * K + sc);
  const u16* Xp = nullptr;
  if constexpr (DUAL)
    Xp = X + (SL ? (size_t)(m0 + sr) * 32 + sc
                 : (size_t)(m0 + sr) * K + sc);
  size_t joff0 = (size_t)(j0 + sr) * K + sc;
  size_t joff1 = joff0 + (size_t)64 * K;
  const int dofs = tid * 8;

  for (int k0 = 0; k0 < K; k0 += TK) {
    __syncthreads();
    gl_lds16(Ap, As + dofs);
    gl_lds16(Ap + rstep, As + 2048 + dofs);
    gl_lds16(Wl + joff0 + k0, Ls + dofs);
    gl_lds16(Wl + joff1 + k0, Ls + 2048 + dofs);
    if constexpr (DUAL) {
      gl_lds16(Xp, Xs + dofs);
      gl_lds16(Xp + rstep, Xs + 2048 + dofs);
      gl_lds16(Wr + joff0 + k0, Rs + dofs);
      gl_lds16(Wr + joff1 + k0, Rs + 2048 + dofs);
      Xp += kstep;
    }
    Ap += kstep;
    __syncthreads();
    {
      short8 af[4], lf[4];
#pragma unroll
      for (int t = 0; t < 4; ++t) {
        af[t] = *(const short8*)(As + (wm + t * 16 + lr) * TK + quad * 8);
        lf[t] = *(const short8*)(Ls + (wn + t * 16 + lr) * TK + quad * 8);
      }
#pragma unroll
      for (int ti = 0; ti < 4; ++ti)
#pragma unroll
        for (int tj = 0; tj < 4; ++tj)
          acc[ti][tj] = __builtin_amdgcn_mfma_f32_16x16x32_bf16(
              af[ti], lf[tj], acc[ti][tj], 0, 0, 0);
    }
    if constexpr (DUAL) {
      short8 xf[4], rf[4];
#pragma unroll
      for (int t = 0; t < 4; ++t) {
        xf[t] = *(const short8*)(Xs + (wm + t * 16 + lr) * TK + quad * 8);
        rf[t] = *(const short8*)(Rs + (wn + t * 16 + lr) * TK + quad * 8);
      }
#pragma unroll
      for (int ti = 0; ti < 4; ++ti)
#pragma unroll
        for (int tj = 0; tj < 4; ++tj)
          acc[ti][tj] = __builtin_amdgcn_mfma_f32_16x16x32_bf16(
              xf[ti], rf[tj], acc[ti][tj], 0, 0, 0);
    }
  }

  // epilogue: C/D layout col=lane&15, row=quad*4+reg (m89-verified)
  if constexpr (OUTMODE == 0) {
    __syncthreads();  // all waves done with staging LDS reads -> reuse as wbuf
    u16* wbuf = smem + wave * 4096;  // wave-private 64x64 u16, XOR-swizzled
    int glo = batch[m0];
    int lastrow = m0 + TM - 1;
    bool fast = (lastrow < N_NODES) && (batch[lastrow] == glo);
#pragma unroll
    for (int tj = 0; tj < 4; ++tj) {
      int gcol = j0 + wn + tj * 16 + lr;
      int cl = tj * 16 + lr;  // local col
      float bv = bias[gcol];
      float s = 0.f, q = 0.f;
#pragma unroll
      for (int ti = 0; ti < 4; ++ti) {
        f32x4 v = acc[ti][tj];
        int rbase = m0 + wm + ti * 16 + quad * 4;
        int rl0 = ti * 16 + quad * 4;  // local row base
        if (fast) {
#pragma unroll
          for (int r = 0; r < 4; ++r) {
            float val = v[r] + bv;
            int rl = rl0 + r;
            int bo = (rl * 128 + cl * 2) ^ (((rl >> 2) & 3) << 5);
            *(u16*)((char*)wbuf + bo) = f2b(val);
            s += val; q += val * val;
          }
        } else {
          if (rbase + 3 < N_NODES && batch[rbase] == batch[rbase + 3]) {
            float s4 = 0.f, q4 = 0.f;
#pragma unroll
            for (int r = 0; r < 4; ++r) {
              float val = v[r] + bv;
              int rl = rl0 + r;
              int bo = (rl * 128 + cl * 2) ^ (((rl >> 2) & 3) << 5);
              *(u16*)((char*)wbuf + bo) = f2b(val);
              s4 += val; q4 += val * val;
            }
            int g = batch[rbase];
            atomicAdd(&ssum[g * H_DIM + gcol], s4);
            atomicAdd(&ssq[g * H_DIM + gcol], q4);
          } else {
#pragma unroll
            for (int r = 0; r < 4; ++r) {
              int grow = rbase + r;
              float val = v[r] + bv;
              int rl = rl0 + r;
              int bo = (rl * 128 + cl * 2) ^ (((rl >> 2) & 3) << 5);
              *(u16*)((char*)wbuf + bo) = f2b(val);  // padding rows land in praw pad
              if (grow < N_NODES) {
                int g = batch[grow];
                atomicAdd(&ssum[g * H_DIM + gcol], val);
                atomicAdd(&ssq[g * H_DIM + gcol], val * val);
              }
            }
          }
        }
      }
      if (fast) {
        s += __shfl_xor(s, 16); s += __shfl_xor(s, 32);
        q += __shfl_xor(q, 16); q += __shfl_xor(q, 32);
        if (quad == 0) {
          atomicAdd(&ssum[glo * H_DIM + gcol], s);
          atomicAdd(&ssq[glo * H_DIM + gcol], q);
        }
      }
    }
    __syncthreads();  // wave's LDS writes complete before read-back
#pragma unroll
    for (int it = 0; it < 8; ++it) {
      int rl = it * 8 + (lane >> 3);
      int c0 = (lane & 7) * 8;
      int bo = (rl * 128 + c0 * 2) ^ (((rl >> 2) & 3) << 5);
      u16x8 vv = *(const u16x8*)((const char*)wbuf + bo);
      *(u16x8*)((u16*)C0 + (size_t)(m0 + wm + rl) * H_DIM + (j0 + wn + c0)) = vv;
    }
  } else {
    if (j0 == 0) {
      // all-u16 block (gcol 0..127): r7-style LDS restage -> coalesced stores
      __syncthreads();
      u16* wbuf = smem + wave * 4096;
#pragma unroll
      for (int tj = 0; tj < 4; ++tj) {
        int cl = tj * 16 + lr;
#pragma unroll
        for (int ti = 0; ti < 4; ++ti) {
          f32x4 v = acc[ti][tj];
          int rl0 = ti * 16 + quad * 4;
#pragma unroll
          for (int r = 0; r < 4; ++r) {
            int rl = rl0 + r;
            int bo = (rl * 128 + cl * 2) ^ (((rl >> 2) & 3) << 5);
            *(u16*)((char*)wbuf + bo) = f2b(v[r]);
          }
        }
      }
      __syncthreads();
#pragma unroll
      for (int it = 0; it < 8; ++it) {
        int rl = it * 8 + (lane >> 3);
        int c0 = (lane & 7) * 8;
        int bo = (rl * 128 + c0 * 2) ^ (((rl >> 2) & 3) << 5);
        u16x8 vv = *(const u16x8*)((const char*)wbuf + bo);
        *(u16x8*)((u16*)C0 + (size_t)(m0 + wm + rl) * 128 + (wn + c0)) = vv;
      }
    } else {
      // all-f32 block (gcol 128..255): 64B-contiguous per 16 lanes already
#pragma unroll
      for (int tj = 0; tj < 4; ++tj) {
        int gc = wn + tj * 16 + lr;  // 0..127 into C1
#pragma unroll
        for (int ti = 0; ti < 4; ++ti) {
          f32x4 v = acc[ti][tj];
#pragma unroll
          for (int r = 0; r < 4; ++r) {
            int grow = m0 + wm + ti * 16 + quad * 4 + r;
            ((float*)C1)[(size_t)grow * 128 + gc] = v[r];
          }
        }
      }
    }
  }
}

// ---------------- GraphNorm: precompute affine, then apply+relu -------------

__global__ void k_precomp(const float* __restrict__ ssum, const float* __restrict__ ssq,
                          const float* __restrict__ inv_sz, const float* __restrict__ gw,
                          const float* __restrict__ gb, const float* __restrict__ alpha,
                          float* __restrict__ S, float* __restrict__ T) {
  int idx = blockIdx.x * blockDim.x + threadIdx.x;
  if (idx >= N_GROUPS * H_DIM) return;
  int g = idx >> 9;
  int c = idx & (H_DIM - 1);
  float is = inv_sz[g];
  float m = ssum[idx] * is;
  float a = alpha[c];
  float var = fmaxf(ssq[idx] * is - a * (2.f - a) * m * m, 0.f);
  float inv = rsqrtf(var + EPSV);
  float sc = inv * gw[c];
  S[idx] = sc;
  T[idx] = gb[c] - a * m * sc;
}

// reads row-major pre-norm GEMM output, writes normalized+relu'd h in the
// SLICED layout (16 x [M_PAD][32] u16 contiguous slices).
__global__ void k_apply(const u16* __restrict__ praw, u16* __restrict__ hs,
                        const int* __restrict__ batch,
                        const float* __restrict__ S, const float* __restrict__ T) {
  int tid = blockIdx.x * blockDim.x + threadIdx.x;
  if (tid >= N_NODES * (H_DIM / 8)) return;
  int n = tid >> 6;
  int c0 = (tid & 63) << 3;
  int g = batch[n];
  u16x8 hv = *(const u16x8*)(praw + (size_t)n * H_DIM + c0);
  u16x8 out;
#pragma unroll
  for (int j = 0; j < 8; ++j) {
    int f = c0 + j;
    float y = b2f(hv[j]) * S[g * H_DIM + f] + T[g * H_DIM + f];
    out[j] = f2b(fmaxf(y, 0.f));
  }
  *(u16x8*)(hs + ((size_t)(c0 >> 5) * M_PAD + n) * 32 + (c0 & 31)) = out;
}

// ---------------- driver ----------------

extern "C" void kernel_launch(void* const* d_in, const int* in_sizes, int n_in,
                              void* d_out, int out_size, void* d_ws, size_t ws_size,
                              hipStream_t stream) {
  const float* x = (const float*)d_in[0];
  const int* edge = (const int*)d_in[1];
  const int* batch = (const int*)d_in[2];
  const float *Wl[5], *Wr[5], *bb[5];
  for (int i = 0; i < 5; ++i) {
    Wl[i] = (const float*)d_in[3 + 3 * i];
    Wr[i] = (const float*)d_in[4 + 3 * i];
    bb[i] = (const float*)d_in[5 + 3 * i];
  }
  const float *gamma[4], *beta[4], *alpha[4];
  for (int i = 0; i < 4; ++i) {
    gamma[i] = (const float*)d_in[18 + 3 * i];
    beta[i]  = (const float*)d_in[19 + 3 * i];
    alpha[i] = (const float*)d_in[20 + 3 * i];
  }
  const int* srcv = edge;
  const int* dstv = edge + N_EDGES;

  char* base = (char*)d_ws;
  size_t off = 0;
  auto carve = [&](size_t bytes) -> char* {
    char* p = base + off;
    off = (off + bytes + 255) & ~(size_t)255;
    return p;
  };
  int* deg       = (int*)carve((size_t)N_NODES * 4);
  float* inv_deg = (float*)carve((size_t)N_NODES * 4);
  int* csr_off   = (int*)carve((size_t)(N_NODES + 1) * 4);
  int* cursor    = (int*)carve((size_t)N_NODES * 4);
  int* csr_src   = (int*)carve((size_t)N_EDGES * 4);
  int* bsum      = (int*)carve((size_t)SCAN_NBLK * 4);
  int* gstart    = (int*)carve((size_t)(N_GROUPS + 1) * 4);
  float* inv_sz  = (float*)carve((size_t)N_GROUPS * 4);
  float* stats   = (float*)carve((size_t)4 * 2 * N_GROUPS * H_DIM * 4);
  float* Sbuf    = (float*)carve((size_t)N_GROUPS * H_DIM * 4);
  float* Tbuf    = (float*)carve((size_t)N_GROUPS * H_DIM * 4);
  u16* xb        = (u16*)carve((size_t)XB_EL * 2);
  u16* aggx      = (u16*)carve((size_t)XB_EL * 2);
  u16* praw      = (u16*)carve((size_t)M_PAD * H_DIM * 2);  // pre-norm GEMM out (rm)
  u16* hsA       = (u16*)carve((size_t)M_PAD * H_DIM * 2);  // normalized h (sliced)
  u16* aggs      = (u16*)carve((size_t)M_PAD * H_DIM * 2);  // aggregated h (sliced)
  u16* wall      = (u16*)carve((size_t)WALL_EL * 2);
  (void)ws_size; (void)in_sizes; (void)n_in; (void)out_size;

  u16* w1lb = wall;
  u16* w1rb = wall + 32768;
  u16* w2lb = wall + 65536;
  u16* w2rb = wall + 327680;
  u16* w3lb = wall + 589824;
  u16* w3rb = wall + 851968;
  u16* w4lb = wall + 1114112;
  u16* w4rb = wall + 1376256;
  u16* w5cat = wall + 1638400;  // 256 x 512

  u16* Plb = aggs;  // layer-5 P split lives in the (dead) aggs region
  float* Prf = (float*)((char*)aggs + (size_t)M_PAD * 128 * 2);

  // graph preprocessing
  hipMemsetAsync(deg, 0, (size_t)N_NODES * 4, stream);
  k_deg<<<(N_EDGES + 255) / 256, 256, 0, stream>>>(dstv, deg);
  k_scan1<<<SCAN_NBLK, SCAN_BLK, 0, stream>>>(deg, csr_off, bsum);
  k_scan2_gbounds<<<2, 256, 0, stream>>>(bsum, batch, gstart, inv_sz);
  k_scan3prep<<<SCAN_NBLK, SCAN_BLK, 0, stream>>>(csr_off, bsum, deg, inv_deg, cursor);
  k_scatter<<<(N_EDGES + 255) / 256, 256, 0, stream>>>(srcv, dstv, cursor, csr_src);

  WcSrc ws_src;
  ws_src.p[0] = Wl[0]; ws_src.p[1] = Wr[0];
  ws_src.p[2] = Wl[1]; ws_src.p[3] = Wr[1];
  ws_src.p[4] = Wl[2]; ws_src.p[5] = Wr[2];
  ws_src.p[6] = Wl[3]; ws_src.p[7] = Wr[3];
  ws_src.p[8] = Wl[4]; ws_src.p[9] = Wr[4];
  k_convert_all<<<(XB_EL + WALL_EL + 255) / 256, 256, 0, stream>>>(x, ws_src, xb, wall);

  hipMemsetAsync(stats, 0, (size_t)4 * 2 * N_GROUPS * H_DIM * 4, stream);

  const int nblk_main = M_TILES * 4;  // JB=4
  const int nblk_l5   = M_TILES * 2;  // JB=2

  auto norm = [&](int l) {
    float* ss = stats + (size_t)l * 2 * N_GROUPS * H_DIM;
    float* sq = ss + N_GROUPS * H_DIM;
    k_precomp<<<(N_GROUPS * H_DIM + 255) / 256, 256, 0, stream>>>(
        ss, sq, inv_sz, gamma[l], beta[l], alpha[l], Sbuf, Tbuf);
    k_apply<<<(N_NODES * (H_DIM / 8) + 255) / 256, 256, 0, stream>>>(
        praw, hsA, batch, Sbuf, Tbuf);
  };
  auto stat_ptr = [&](int l) { return stats + (size_t)l * 2 * N_GROUPS * H_DIM; };
  auto agg = [&]() {
    k_agg_slice<<<AGG_BLKS, 256, 0, stream>>>(hsA, csr_off, csr_src, inv_deg, aggs, 0);
    k_agg_slice<<<AGG_BLKS, 256, 0, stream>>>(hsA, csr_off, csr_src, inv_deg, aggs, 1);
  };

  // layer 1 (K = 64 padded, row-major operands)
  k_agg_small<<<N_NODES, 64, 0, stream>>>(xb, csr_off, csr_src, inv_deg, aggx);
  k_gemm_mfma<4, true, 0, false><<<nblk_main, 256, 0, stream>>>(
      aggx, xb, w1lb, w1rb, bb[0], praw, nullptr, batch,
      stat_ptr(0), stat_ptr(0) + N_GROUPS * H_DIM, K1PAD);
  norm(0);

  // layers 2..4: sliced gather (one slice-set per dispatch) + sliced GEMM
  agg();
  k_gemm_mfma<4, true, 0, true><<<nblk_main, 256, 0, stream>>>(
      aggs, hsA, w2lb, w2rb, bb[1], praw, nullptr, batch,
      stat_ptr(1), stat_ptr(1) + N_GROUPS * H_DIM, H_DIM);
  norm(1);

  agg();
  k_gemm_mfma<4, true, 0, true><<<nblk_main, 256, 0, stream>>>(
      aggs, hsA, w3lb, w3rb, bb[2], praw, nullptr, batch,
      stat_ptr(2), stat_ptr(2) + N_GROUPS * H_DIM, H_DIM);
  norm(2);

  agg();
  k_gemm_mfma<4, true, 0, true><<<nblk_main, 256, 0, stream>>>(
      aggs, hsA, w4lb, w4rb, bb[3], praw, nullptr, batch,
      stat_ptr(3), stat_ptr(3) + N_GROUPS * H_DIM, H_DIM);
  norm(3);

  // layer 5 via linearity: P = h @ [W5l|W5r]^T (J=256), then
  // out = inv_deg * segsum(Pl[src]) + Pr + b5
  k_gemm_mfma<2, false, 1, true><<<nblk_l5, 256, 0, stream>>>(
      hsA, nullptr, w5cat, nullptr, nullptr, Plb, Prf, nullptr, nullptr, nullptr, H_DIM);
  k_agg_final<<<(N_NODES + 7) / 8, 256, 0, stream>>>(
      Plb, Prf, csr_off, csr_src, inv_deg, bb[4], (float*)d_out);
}

// Round 10
// 992.130 us; speedup vs baseline: 1.0879x; 1.0117x over previous
//
#include <hip/hip_runtime.h>
#include <cstddef>
#include <cstdint>

#define N_NODES 50000
#define N_EDGES 800000
#define F_IN 50
#define K1PAD 64
#define H_DIM 512
#define O_DIM 121
#define N_GROUPS 20
#define EPSV 1e-5f
#define M_PAD 50176   // 392 * 128
#define M_TILES 392

#define SCAN_BLK 256
#define SCAN_NBLK ((N_NODES + SCAN_BLK - 1) / SCAN_BLK)  // 196
#define WALL_EL 1769472
#define XB_EL (M_PAD * K1PAD)

typedef unsigned short u16;
typedef __attribute__((ext_vector_type(8))) short short8;          // 8 bf16 (4 VGPRs)
typedef __attribute__((ext_vector_type(8))) unsigned short u16x8;  // 16B vector load
typedef __attribute__((ext_vector_type(4))) float f32x4;
typedef __attribute__((ext_vector_type(2))) float f32x2;

__device__ __forceinline__ float b2f(u16 u) {
  union { unsigned int i; float f; } v; v.i = ((unsigned int)u) << 16; return v.f;
}
__device__ __forceinline__ u16 f2b(float f) {
  union { float f; unsigned int i; } v; v.f = f;
  unsigned int x = v.i;
  return (u16)((x + 0x7fffu + ((x >> 16) & 1u)) >> 16);  // RNE
}

// unpack one dword (2 bf16) to f32x2 {lo, hi}: 2 VALU + downstream pk-adds
__device__ __forceinline__ f32x2 up2(unsigned int d) {
  union { unsigned int u; float f; } lo, hi;
  lo.u = d << 16;
  hi.u = d & 0xffff0000u;
  f32x2 r; r.x = lo.f; r.y = hi.f;
  return r;
}

__device__ __forceinline__ void gl_lds16(const void* g, void* l) {
  __builtin_amdgcn_global_load_lds(
      (__attribute__((address_space(1))) void*)(g),
      (__attribute__((address_space(3))) void*)(l), 16, 0, 0);
}

// ---------------- graph preprocessing ----------------

__global__ void k_deg(const int* __restrict__ dst, int* __restrict__ deg) {
  int e = blockIdx.x * blockDim.x + threadIdx.x;
  if (e < N_EDGES) atomicAdd(&deg[dst[e]], 1);
}

__global__ void k_scan1(const int* __restrict__ deg, int* __restrict__ off,
                        int* __restrict__ bsum) {
  __shared__ int buf[SCAN_BLK];
  int gid = blockIdx.x * SCAN_BLK + threadIdx.x;
  buf[threadIdx.x] = (gid < N_NODES) ? deg[gid] : 0;
  __syncthreads();
  for (int d = 1; d < SCAN_BLK; d <<= 1) {
    int t = (threadIdx.x >= d) ? buf[threadIdx.x - d] : 0;
    __syncthreads();
    buf[threadIdx.x] += t;
    __syncthreads();
  }
  if (gid < N_NODES) off[gid + 1] = buf[threadIdx.x];
  if (threadIdx.x == SCAN_BLK - 1) bsum[blockIdx.x] = buf[threadIdx.x];
}

// block 0: scan of block sums; block 1: group bounds from sorted batch
__global__ void k_scan2_gbounds(int* __restrict__ bsum, const int* __restrict__ batch,
                                int* __restrict__ gstart, float* __restrict__ inv_sz) {
  int t = threadIdx.x;
  if (blockIdx.x == 0) {
    __shared__ int buf[256];
    buf[t] = (t < SCAN_NBLK) ? bsum[t] : 0;
    __syncthreads();
    for (int d = 1; d < 256; d <<= 1) {
      int v = (t >= d) ? buf[t - d] : 0;
      __syncthreads();
      buf[t] += v;
      __syncthreads();
    }
    if (t < SCAN_NBLK) bsum[t] = buf[t];
  } else {
    if (t <= N_GROUPS) {
      int lo = 0, hi = N_NODES;
      while (lo < hi) {
        int mid = (lo + hi) >> 1;
        if (batch[mid] < t) lo = mid + 1; else hi = mid;
      }
      gstart[t] = lo;
    }
    __syncthreads();
    if (t < N_GROUPS) {
      int sz = gstart[t + 1] - gstart[t];
      inv_sz[t] = 1.0f / (float)max(sz, 1);
    }
  }
}

__global__ void k_scan3prep(int* __restrict__ off, const int* __restrict__ bsum,
                            const int* __restrict__ deg, float* __restrict__ inv_deg,
                            int* __restrict__ cursor) {
  int gid = blockIdx.x * SCAN_BLK + threadIdx.x;
  if (gid < N_NODES) {
    int add = (blockIdx.x > 0) ? bsum[blockIdx.x - 1] : 0;
    int v = off[gid + 1] + add;
    off[gid + 1] = v;
    if (gid + 1 < N_NODES) cursor[gid + 1] = v;
    inv_deg[gid] = 1.0f / (float)max(deg[gid], 1);
  }
  if (gid == 0) { off[0] = 0; cursor[0] = 0; }
}

__global__ void k_scatter(const int* __restrict__ src, const int* __restrict__ dst,
                          int* __restrict__ cursor, int* __restrict__ csr_src) {
  int e = blockIdx.x * blockDim.x + threadIdx.x;
  if (e < N_EDGES) {
    int p = atomicAdd(&cursor[dst[e]], 1);
    csr_src[p] = src[e];
  }
}

// ---------------- conversions (x pad + all weights, one launch) -------------
struct WcSrc { const float* p[10]; };
__global__ void k_convert_all(const float* __restrict__ x, WcSrc s,
                              u16* __restrict__ xb, u16* __restrict__ wall) {
  int idx = blockIdx.x * blockDim.x + threadIdx.x;
  if (idx < XB_EL) {
    int r = idx >> 6, c = idx & (K1PAD - 1);
    float v = (r < N_NODES && c < F_IN) ? x[r * F_IN + c] : 0.f;
    xb[idx] = f2b(v);
    return;
  }
  idx -= XB_EL;
  if (idx >= WALL_EL) return;
  const int seg_start[10] = {0, 32768, 65536, 327680, 589824, 851968,
                             1114112, 1376256, 1638400, 1703936};
  const int jr[10]  = {512, 512, 512, 512, 512, 512, 512, 512, 121, 121};
  const int kin[10] = {50, 50, 512, 512, 512, 512, 512, 512, 512, 512};
  const int ksh[10] = {6, 6, 9, 9, 9, 9, 9, 9, 9, 9};
  int sgi = 0;
#pragma unroll
  for (int t = 1; t < 10; ++t)
    if (idx >= seg_start[t]) sgi = t;
  int local = idx - seg_start[sgi];
  int j = local >> ksh[sgi];
  int k = local & ((1 << ksh[sgi]) - 1);
  float v = (j < jr[sgi] && k < kin[sgi]) ? s.p[sgi][j * kin[sgi] + k] : 0.f;
  wall[idx] = f2b(v);
}

// ---------------- aggregation ----------------

// layer 1 gather: wave-per-node grid-stride (natural order), 4-edge unroll.
// r10: replaces the original 50000 one-wave blocks (no MLP, serial edge
// loop) with the proven agg-family shape: 1024 blocks x 4 waves, each wave
// owns one 64-col row (lane f = 2B of the 128B row), 4 loads in flight.
#define AGS_WAVES 4096
__global__ __launch_bounds__(256) void k_agg_small(
    const u16* __restrict__ xb, const int* __restrict__ off,
    const int* __restrict__ srcs, const float* __restrict__ inv_deg,
    u16* __restrict__ agg) {
  int wid = blockIdx.x * 4 + (threadIdx.x >> 6);
  int f = threadIdx.x & 63;
  for (int n = wid; n < N_NODES; n += AGS_WAVES) {
    int b = off[n], e = off[n + 1];
    float s = 0.f;
    int i = b;
    for (; i + 4 <= e; i += 4) {
      float s0 = b2f(xb[(size_t)srcs[i + 0] * K1PAD + f]);
      float s1 = b2f(xb[(size_t)srcs[i + 1] * K1PAD + f]);
      float s2 = b2f(xb[(size_t)srcs[i + 2] * K1PAD + f]);
      float s3 = b2f(xb[(size_t)srcs[i + 3] * K1PAD + f]);
      s += (s0 + s1) + (s2 + s3);
    }
    for (; i < e; ++i) s += b2f(xb[(size_t)srcs[i] * K1PAD + f]);
    agg[(size_t)n * K1PAD + f] = f2b(s * inv_deg[n]);
  }
}

// layers 2..4 aggregation, XCD-sliced. h stored SLICED: 16 regions of
// [M_PAD][32] u16 (3.2MB each); slice s = xcd*2+ph processed only by blocks
// on XCD s>>1 (blockIdx&7 -> XCD round-robin).
// ONE PHASE PER DISPATCH (r4: both phases resident -> 2 slices + CSR > 4MB
// L2 -> thrash). NATURAL node order (r3/r6: reordering perms broke CSR/write
// locality). 4-edge unroll EXACTLY (r7: 8-unroll regressed).
// f32x2 accumulate (v_pk_add_f32), bit-identical per-channel order (r9).
#define AGG_BLKS 2048  // 256 chunks x 8 XCDs
__global__ __launch_bounds__(256) void k_agg_slice(
    const u16* __restrict__ hs, const int* __restrict__ off,
    const int* __restrict__ srcs, const float* __restrict__ inv_deg,
    u16* __restrict__ aggs, int ph) {
  const int xcd = blockIdx.x & 7;
  const int chunk = blockIdx.x >> 3;                 // 0..255
  const int nchunk = AGG_BLKS / 8;                   // 256
  const int per = (N_NODES + nchunk - 1) / nchunk;   // 196
  const int p0 = chunk * per;
  const int p1 = min(p0 + per, N_NODES);
  const int grp = threadIdx.x >> 2;       // 0..63 node-groups per block
  const int sub = (threadIdx.x & 3) * 8;  // u16 offset of this lane's 16B
  const int s = xcd * 2 + ph;
  const u16* hsl = hs + (size_t)s * M_PAD * 32 + sub;
  u16* asl = aggs + (size_t)s * M_PAD * 32 + sub;
  for (int n = p0 + grp; n < p1; n += 64) {
    int b = off[n], e = off[n + 1];
    f32x2 a0 = {0.f, 0.f}, a1 = {0.f, 0.f}, a2 = {0.f, 0.f}, a3 = {0.f, 0.f};
    int i = b;
    for (; i + 4 <= e; i += 4) {
      uint4 w0 = *(const uint4*)(hsl + (size_t)srcs[i + 0] * 32);
      uint4 w1 = *(const uint4*)(hsl + (size_t)srcs[i + 1] * 32);
      uint4 w2 = *(const uint4*)(hsl + (size_t)srcs[i + 2] * 32);
      uint4 w3 = *(const uint4*)(hsl + (size_t)srcs[i + 3] * 32);
      a0 += (up2(w0.x) + up2(w1.x)) + (up2(w2.x) + up2(w3.x));
      a1 += (up2(w0.y) + up2(w1.y)) + (up2(w2.y) + up2(w3.y));
      a2 += (up2(w0.z) + up2(w1.z)) + (up2(w2.z) + up2(w3.z));
      a3 += (up2(w0.w) + up2(w1.w)) + (up2(w2.w) + up2(w3.w));
    }
    for (; i < e; ++i) {
      uint4 w0 = *(const uint4*)(hsl + (size_t)srcs[i] * 32);
      a0 += up2(w0.x); a1 += up2(w0.y); a2 += up2(w0.z); a3 += up2(w0.w);
    }
    float iw = inv_deg[n];
    u16x8 r;
    r[0] = f2b(a0.x * iw); r[1] = f2b(a0.y * iw);
    r[2] = f2b(a1.x * iw); r[3] = f2b(a1.y * iw);
    r[4] = f2b(a2.x * iw); r[5] = f2b(a2.y * iw);
    r[6] = f2b(a3.x * iw); r[7] = f2b(a3.y * iw);
    *(u16x8*)(asl + (size_t)n * 32) = r;
  }
}

// layer 5 final: out[n] = inv_deg[n]*sum(Pl[src]) + Pr[n] + bias (121 cols)
// r10: 4-edge unroll (MLP 2 -> 4), pairwise adds, natural order preserved.
__global__ __launch_bounds__(256) void k_agg_final(
    const u16* __restrict__ Plb, const float* __restrict__ Prf,
    const int* __restrict__ off, const int* __restrict__ srcs,
    const float* __restrict__ inv_deg, const float* __restrict__ bias,
    float* __restrict__ out) {
  int n = blockIdx.x * 8 + (threadIdx.x >> 5);
  if (n >= N_NODES) return;
  int l = threadIdx.x & 31;
  int c0 = l * 4;
  int b = off[n], e = off[n + 1];
  float a0 = 0.f, a1 = 0.f, a2 = 0.f, a3 = 0.f;
  int i = b;
  for (; i + 4 <= e; i += 4) {
    ushort4 v0 = ((const ushort4*)(Plb + (size_t)srcs[i + 0] * 128))[l];
    ushort4 v1 = ((const ushort4*)(Plb + (size_t)srcs[i + 1] * 128))[l];
    ushort4 v2 = ((const ushort4*)(Plb + (size_t)srcs[i + 2] * 128))[l];
    ushort4 v3 = ((const ushort4*)(Plb + (size_t)srcs[i + 3] * 128))[l];
    a0 += (b2f(v0.x) + b2f(v1.x)) + (b2f(v2.x) + b2f(v3.x));
    a1 += (b2f(v0.y) + b2f(v1.y)) + (b2f(v2.y) + b2f(v3.y));
    a2 += (b2f(v0.z) + b2f(v1.z)) + (b2f(v2.z) + b2f(v3.z));
    a3 += (b2f(v0.w) + b2f(v1.w)) + (b2f(v2.w) + b2f(v3.w));
  }
  for (; i < e; ++i) {
    ushort4 v0 = ((const ushort4*)(Plb + (size_t)srcs[i] * 128))[l];
    a0 += b2f(v0.x); a1 += b2f(v0.y); a2 += b2f(v0.z); a3 += b2f(v0.w);
  }
  float w = inv_deg[n];
  float4 pr = ((const float4*)(Prf + (size_t)n * 128))[l];
  float r0 = a0 * w + pr.x, r1 = a1 * w + pr.y;
  float r2 = a2 * w + pr.z, r3 = a3 * w + pr.w;
  size_t ob = (size_t)n * O_DIM;
  if (c0 + 0 < O_DIM) out[ob + c0 + 0] = r0 + bias[c0 + 0];
  if (c0 + 1 < O_DIM) out[ob + c0 + 1] = r1 + bias[c0 + 1];
  if (c0 + 2 < O_DIM) out[ob + c0 + 2] = r2 + bias[c0 + 2];
  if (c0 + 3 < O_DIM) out[ob + c0 + 3] = r3 + bias[c0 + 3];
}

// ---------------- MFMA GEMM ----------------
// DUAL(OUTMODE 0): C = A*Wl^T + X*Wr^T + b, bf16 out [*, 512]; GraphNorm
//   stats fused in epilogue. !DUAL(OUTMODE 1): P = A*Wl^T split bf16/f32.
// SL: A/X in the 16x[M_PAD][32] sliced layout.
// K-loop: simple 2-barrier form (r6: counted-vmcnt pipeline regressed via
//   occupancy). EPILOGUE (r7-verified WIN on OUTMODE 0: WRITE 83->57.6MB,
//   dur 98->86): stage the wave's 64x64 bf16 tile into its dead staging
//   LDS, XOR-swizzled, then 8 coalesced full-128B-segment stores.
//   OUTMODE 1's u16 half gets the same treatment (r9).

#define TM 128
#define TK 32

template <int JB, bool DUAL, int OUTMODE, bool SL>
__global__ __launch_bounds__(256, 4) void k_gemm_mfma(
    const u16* __restrict__ A, const u16* __restrict__ X,
    const u16* __restrict__ Wl, const u16* __restrict__ Wr,
    const float* __restrict__ bias, void* __restrict__ C0,
    void* __restrict__ C1, const int* __restrict__ batch,
    float* __restrict__ ssum, float* __restrict__ ssq, int K) {
  __shared__ u16 smem[(DUAL || OUTMODE == 1) ? 16384 : 8192];
  u16* As = smem;
  u16* Ls = smem + 4096;
  u16* Xs = DUAL ? smem + 8192 : smem;
  u16* Rs = DUAL ? smem + 12288 : smem;

  int id = blockIdx.x;
  const int nfull = (M_TILES >> 3) * 8 * JB;
  int m_t, j_t;
  if (id < nfull) {
    m_t = (id / (8 * JB)) * 8 + (id & 7);
    j_t = (id >> 3) & (JB - 1);
  } else {
    int rem = id - nfull;
    const int nrem = (M_TILES & 7) ? (M_TILES & 7) : 1;
    m_t = (M_TILES & ~7) + rem % nrem;
    j_t = rem / nrem;
  }
  int m0 = m_t * TM;
  int j0 = j_t * 128;

  int tid = threadIdx.x;
  int lane = tid & 63;
  int wave = tid >> 6;
  int quad = lane >> 4;
  int lr = lane & 15;
  int wm = (wave & 1) * 64;
  int wn = (wave >> 1) * 64;

  f32x4 acc[4][4] = {};

  int sr = tid >> 2;
  int sc = (tid & 3) * 8;
  const size_t kstep = SL ? (size_t)M_PAD * 32 : (size_t)TK;
  const size_t rstep = SL ? (size_t)64 * 32 : (size_t)64 * K;
  const u16* Ap = A + (SL ? (size_t)(m0 + sr) * 32 + sc
                          : (size_t)(m0 + sr) * K + sc);
  const u16* Xp = nullptr;
  if constexpr (DUAL)
    Xp = X + (SL ? (size_t)(m0 + sr) * 32 + sc
                 : (size_t)(m0 + sr) * K + sc);
  size_t joff0 = (size_t)(j0 + sr) * K + sc;
  size_t joff1 = joff0 + (size_t)64 * K;
  const int dofs = tid * 8;

  for (int k0 = 0; k0 < K; k0 += TK) {
    __syncthreads();
    gl_lds16(Ap, As + dofs);
    gl_lds16(Ap + rstep, As + 2048 + dofs);
    gl_lds16(Wl + joff0 + k0, Ls + dofs);
    gl_lds16(Wl + joff1 + k0, Ls + 2048 + dofs);
    if constexpr (DUAL) {
      gl_lds16(Xp, Xs + dofs);
      gl_lds16(Xp + rstep, Xs + 2048 + dofs);
      gl_lds16(Wr + joff0 + k0, Rs + dofs);
      gl_lds16(Wr + joff1 + k0, Rs + 2048 + dofs);
      Xp += kstep;
    }
    Ap += kstep;
    __syncthreads();
    {
      short8 af[4], lf[4];
#pragma unroll
      for (int t = 0; t < 4; ++t) {
        af[t] = *(const short8*)(As + (wm + t * 16 + lr) * TK + quad * 8);
        lf[t] = *(const short8*)(Ls + (wn + t * 16 + lr) * TK + quad * 8);
      }
#pragma unroll
      for (int ti = 0; ti < 4; ++ti)
#pragma unroll
        for (int tj = 0; tj < 4; ++tj)
          acc[ti][tj] = __builtin_amdgcn_mfma_f32_16x16x32_bf16(
              af[ti], lf[tj], acc[ti][tj], 0, 0, 0);
    }
    if constexpr (DUAL) {
      short8 xf[4], rf[4];
#pragma unroll
      for (int t = 0; t < 4; ++t) {
        xf[t] = *(const short8*)(Xs + (wm + t * 16 + lr) * TK + quad * 8);
        rf[t] = *(const short8*)(Rs + (wn + t * 16 + lr) * TK + quad * 8);
      }
#pragma unroll
      for (int ti = 0; ti < 4; ++ti)
#pragma unroll
        for (int tj = 0; tj < 4; ++tj)
          acc[ti][tj] = __builtin_amdgcn_mfma_f32_16x16x32_bf16(
              xf[ti], rf[tj], acc[ti][tj], 0, 0, 0);
    }
  }

  // epilogue: C/D layout col=lane&15, row=quad*4+reg (m89-verified)
  if constexpr (OUTMODE == 0) {
    __syncthreads();  // all waves done with staging LDS reads -> reuse as wbuf
    u16* wbuf = smem + wave * 4096;  // wave-private 64x64 u16, XOR-swizzled
    int glo = batch[m0];
    int lastrow = m0 + TM - 1;
    bool fast = (lastrow < N_NODES) && (batch[lastrow] == glo);
#pragma unroll
    for (int tj = 0; tj < 4; ++tj) {
      int gcol = j0 + wn + tj * 16 + lr;
      int cl = tj * 16 + lr;  // local col
      float bv = bias[gcol];
      float s = 0.f, q = 0.f;
#pragma unroll
      for (int ti = 0; ti < 4; ++ti) {
        f32x4 v = acc[ti][tj];
        int rbase = m0 + wm + ti * 16 + quad * 4;
        int rl0 = ti * 16 + quad * 4;  // local row base
        if (fast) {
#pragma unroll
          for (int r = 0; r < 4; ++r) {
            float val = v[r] + bv;
            int rl = rl0 + r;
            int bo = (rl * 128 + cl * 2) ^ (((rl >> 2) & 3) << 5);
            *(u16*)((char*)wbuf + bo) = f2b(val);
            s += val; q += val * val;
          }
        } else {
          if (rbase + 3 < N_NODES && batch[rbase] == batch[rbase + 3]) {
            float s4 = 0.f, q4 = 0.f;
#pragma unroll
            for (int r = 0; r < 4; ++r) {
              float val = v[r] + bv;
              int rl = rl0 + r;
              int bo = (rl * 128 + cl * 2) ^ (((rl >> 2) & 3) << 5);
              *(u16*)((char*)wbuf + bo) = f2b(val);
              s4 += val; q4 += val * val;
            }
            int g = batch[rbase];
            atomicAdd(&ssum[g * H_DIM + gcol], s4);
            atomicAdd(&ssq[g * H_DIM + gcol], q4);
          } else {
#pragma unroll
            for (int r = 0; r < 4; ++r) {
              int grow = rbase + r;
              float val = v[r] + bv;
              int rl = rl0 + r;
              int bo = (rl * 128 + cl * 2) ^ (((rl >> 2) & 3) << 5);
              *(u16*)((char*)wbuf + bo) = f2b(val);  // padding rows land in praw pad
              if (grow < N_NODES) {
                int g = batch[grow];
                atomicAdd(&ssum[g * H_DIM + gcol], val);
                atomicAdd(&ssq[g * H_DIM + gcol], val * val);
              }
            }
          }
        }
      }
      if (fast) {
        s += __shfl_xor(s, 16); s += __shfl_xor(s, 32);
        q += __shfl_xor(q, 16); q += __shfl_xor(q, 32);
        if (quad == 0) {
          atomicAdd(&ssum[glo * H_DIM + gcol], s);
          atomicAdd(&ssq[glo * H_DIM + gcol], q);
        }
      }
    }
    __syncthreads();  // wave's LDS writes complete before read-back
#pragma unroll
    for (int it = 0; it < 8; ++it) {
      int rl = it * 8 + (lane >> 3);
      int c0 = (lane & 7) * 8;
      int bo = (rl * 128 + c0 * 2) ^ (((rl >> 2) & 3) << 5);
      u16x8 vv = *(const u16x8*)((const char*)wbuf + bo);
      *(u16x8*)((u16*)C0 + (size_t)(m0 + wm + rl) * H_DIM + (j0 + wn + c0)) = vv;
    }
  } else {
    if (j0 == 0) {
      // all-u16 block (gcol 0..127): r7-style LDS restage -> coalesced stores
      __syncthreads();
      u16* wbuf = smem + wave * 4096;
#pragma unroll
      for (int tj = 0; tj < 4; ++tj) {
        int cl = tj * 16 + lr;
#pragma unroll
        for (int ti = 0; ti < 4; ++ti) {
          f32x4 v = acc[ti][tj];
          int rl0 = ti * 16 + quad * 4;
#pragma unroll
          for (int r = 0; r < 4; ++r) {
            int rl = rl0 + r;
            int bo = (rl * 128 + cl * 2) ^ (((rl >> 2) & 3) << 5);
            *(u16*)((char*)wbuf + bo) = f2b(v[r]);
          }
        }
      }
      __syncthreads();
#pragma unroll
      for (int it = 0; it < 8; ++it) {
        int rl = it * 8 + (lane >> 3);
        int c0 = (lane & 7) * 8;
        int bo = (rl * 128 + c0 * 2) ^ (((rl >> 2) & 3) << 5);
        u16x8 vv = *(const u16x8*)((const char*)wbuf + bo);
        *(u16x8*)((u16*)C0 + (size_t)(m0 + wm + rl) * 128 + (wn + c0)) = vv;
      }
    } else {
      // all-f32 block (gcol 128..255): 64B-contiguous per 16 lanes already
#pragma unroll
      for (int tj = 0; tj < 4; ++tj) {
        int gc = wn + tj * 16 + lr;  // 0..127 into C1
#pragma unroll
        for (int ti = 0; ti < 4; ++ti) {
          f32x4 v = acc[ti][tj];
#pragma unroll
          for (int r = 0; r < 4; ++r) {
            int grow = m0 + wm + ti * 16 + quad * 4 + r;
            ((float*)C1)[(size_t)grow * 128 + gc] = v[r];
          }
        }
      }
    }
  }
}

// ---------------- GraphNorm: precompute affine, then apply+relu -------------

__global__ void k_precomp(const float* __restrict__ ssum, const float* __restrict__ ssq,
                          const float* __restrict__ inv_sz, const float* __restrict__ gw,
                          const float* __restrict__ gb, const float* __restrict__ alpha,
                          float* __restrict__ S, float* __restrict__ T) {
  int idx = blockIdx.x * blockDim.x + threadIdx.x;
  if (idx >= N_GROUPS * H_DIM) return;
  int g = idx >> 9;
  int c = idx & (H_DIM - 1);
  float is = inv_sz[g];
  float m = ssum[idx] * is;
  float a = alpha[c];
  float var = fmaxf(ssq[idx] * is - a * (2.f - a) * m * m, 0.f);
  float inv = rsqrtf(var + EPSV);
  float sc = inv * gw[c];
  S[idx] = sc;
  T[idx] = gb[c] - a * m * sc;
}

// reads row-major pre-norm GEMM output, writes normalized+relu'd h in the
// SLICED layout (16 x [M_PAD][32] u16 contiguous slices).
__global__ void k_apply(const u16* __restrict__ praw, u16* __restrict__ hs,
                        const int* __restrict__ batch,
                        const float* __restrict__ S, const float* __restrict__ T) {
  int tid = blockIdx.x * blockDim.x + threadIdx.x;
  if (tid >= N_NODES * (H_DIM / 8)) return;
  int n = tid >> 6;
  int c0 = (tid & 63) << 3;
  int g = batch[n];
  u16x8 hv = *(const u16x8*)(praw + (size_t)n * H_DIM + c0);
  u16x8 out;
#pragma unroll
  for (int j = 0; j < 8; ++j) {
    int f = c0 + j;
    float y = b2f(hv[j]) * S[g * H_DIM + f] + T[g * H_DIM + f];
    out[j] = f2b(fmaxf(y, 0.f));
  }
  *(u16x8*)(hs + ((size_t)(c0 >> 5) * M_PAD + n) * 32 + (c0 & 31)) = out;
}

// ---------------- driver ----------------

extern "C" void kernel_launch(void* const* d_in, const int* in_sizes, int n_in,
                              void* d_out, int out_size, void* d_ws, size_t ws_size,
                              hipStream_t stream) {
  const float* x = (const float*)d_in[0];
  const int* edge = (const int*)d_in[1];
  const int* batch = (const int*)d_in[2];
  const float *Wl[5], *Wr[5], *bb[5];
  for (int i = 0; i < 5; ++i) {
    Wl[i] = (const float*)d_in[3 + 3 * i];
    Wr[i] = (const float*)d_in[4 + 3 * i];
    bb[i] = (const float*)d_in[5 + 3 * i];
  }
  const float *gamma[4], *beta[4], *alpha[4];
  for (int i = 0; i < 4; ++i) {
    gamma[i] = (const float*)d_in[18 + 3 * i];
    beta[i]  = (const float*)d_in[19 + 3 * i];
    alpha[i] = (const float*)d_in[20 + 3 * i];
  }
  const int* srcv = edge;
  const int* dstv = edge + N_EDGES;

  char* base = (char*)d_ws;
  size_t off = 0;
  auto carve = [&](size_t bytes) -> char* {
    char* p = base + off;
    off = (off + bytes + 255) & ~(size_t)255;
    return p;
  };
  int* deg       = (int*)carve((size_t)N_NODES * 4);
  float* inv_deg = (float*)carve((size_t)N_NODES * 4);
  int* csr_off   = (int*)carve((size_t)(N_NODES + 1) * 4);
  int* cursor    = (int*)carve((size_t)N_NODES * 4);
  int* csr_src   = (int*)carve((size_t)N_EDGES * 4);
  int* bsum      = (int*)carve((size_t)SCAN_NBLK * 4);
  int* gstart    = (int*)carve((size_t)(N_GROUPS + 1) * 4);
  float* inv_sz  = (float*)carve((size_t)N_GROUPS * 4);
  float* stats   = (float*)carve((size_t)4 * 2 * N_GROUPS * H_DIM * 4);
  float* Sbuf    = (float*)carve((size_t)N_GROUPS * H_DIM * 4);
  float* Tbuf    = (float*)carve((size_t)N_GROUPS * H_DIM * 4);
  u16* xb        = (u16*)carve((size_t)XB_EL * 2);
  u16* aggx      = (u16*)carve((size_t)XB_EL * 2);
  u16* praw      = (u16*)carve((size_t)M_PAD * H_DIM * 2);  // pre-norm GEMM out (rm)
  u16* hsA       = (u16*)carve((size_t)M_PAD * H_DIM * 2);  // normalized h (sliced)
  u16* aggs      = (u16*)carve((size_t)M_PAD * H_DIM * 2);  // aggregated h (sliced)
  u16* wall      = (u16*)carve((size_t)WALL_EL * 2);
  (void)ws_size; (void)in_sizes; (void)n_in; (void)out_size;

  u16* w1lb = wall;
  u16* w1rb = wall + 32768;
  u16* w2lb = wall + 65536;
  u16* w2rb = wall + 327680;
  u16* w3lb = wall + 589824;
  u16* w3rb = wall + 851968;
  u16* w4lb = wall + 1114112;
  u16* w4rb = wall + 1376256;
  u16* w5cat = wall + 1638400;  // 256 x 512

  u16* Plb = aggs;  // layer-5 P split lives in the (dead) aggs region
  float* Prf = (float*)((char*)aggs + (size_t)M_PAD * 128 * 2);

  // graph preprocessing
  hipMemsetAsync(deg, 0, (size_t)N_NODES * 4, stream);
  k_deg<<<(N_EDGES + 255) / 256, 256, 0, stream>>>(dstv, deg);
  k_scan1<<<SCAN_NBLK, SCAN_BLK, 0, stream>>>(deg, csr_off, bsum);
  k_scan2_gbounds<<<2, 256, 0, stream>>>(bsum, batch, gstart, inv_sz);
  k_scan3prep<<<SCAN_NBLK, SCAN_BLK, 0, stream>>>(csr_off, bsum, deg, inv_deg, cursor);
  k_scatter<<<(N_EDGES + 255) / 256, 256, 0, stream>>>(srcv, dstv, cursor, csr_src);

  WcSrc ws_src;
  ws_src.p[0] = Wl[0]; ws_src.p[1] = Wr[0];
  ws_src.p[2] = Wl[1]; ws_src.p[3] = Wr[1];
  ws_src.p[4] = Wl[2]; ws_src.p[5] = Wr[2];
  ws_src.p[6] = Wl[3]; ws_src.p[7] = Wr[3];
  ws_src.p[8] = Wl[4]; ws_src.p[9] = Wr[4];
  k_convert_all<<<(XB_EL + WALL_EL + 255) / 256, 256, 0, stream>>>(x, ws_src, xb, wall);

  hipMemsetAsync(stats, 0, (size_t)4 * 2 * N_GROUPS * H_DIM * 4, stream);

  const int nblk_main = M_TILES * 4;  // JB=4
  const int nblk_l5   = M_TILES * 2;  // JB=2

  auto norm = [&](int l) {
    float* ss = stats + (size_t)l * 2 * N_GROUPS * H_DIM;
    float* sq = ss + N_GROUPS * H_DIM;
    k_precomp<<<(N_GROUPS * H_DIM + 255) / 256, 256, 0, stream>>>(
        ss, sq, inv_sz, gamma[l], beta[l], alpha[l], Sbuf, Tbuf);
    k_apply<<<(N_NODES * (H_DIM / 8) + 255) / 256, 256, 0, stream>>>(
        praw, hsA, batch, Sbuf, Tbuf);
  };
  auto stat_ptr = [&](int l) { return stats + (size_t)l * 2 * N_GROUPS * H_DIM; };
  auto agg = [&]() {
    k_agg_slice<<<AGG_BLKS, 256, 0, stream>>>(hsA, csr_off, csr_src, inv_deg, aggs, 0);
    k_agg_slice<<<AGG_BLKS, 256, 0, stream>>>(hsA, csr_off, csr_src, inv_deg, aggs, 1);
  };

  // layer 1 (K = 64 padded, row-major operands)
  k_agg_small<<<AGS_WAVES / 4, 256, 0, stream>>>(xb, csr_off, csr_src, inv_deg, aggx);
  k_gemm_mfma<4, true, 0, false><<<nblk_main, 256, 0, stream>>>(
      aggx, xb, w1lb, w1rb, bb[0], praw, nullptr, batch,
      stat_ptr(0), stat_ptr(0) + N_GROUPS * H_DIM, K1PAD);
  norm(0);

  // layers 2..4: sliced gather (one slice-set per dispatch) + sliced GEMM
  agg();
  k_gemm_mfma<4, true, 0, true><<<nblk_main, 256, 0, stream>>>(
      aggs, hsA, w2lb, w2rb, bb[1], praw, nullptr, batch,
      stat_ptr(1), stat_ptr(1) + N_GROUPS * H_DIM, H_DIM);
  norm(1);

  agg();
  k_gemm_mfma<4, true, 0, true><<<nblk_main, 256, 0, stream>>>(
      aggs, hsA, w3lb, w3rb, bb[2], praw, nullptr, batch,
      stat_ptr(2), stat_ptr(2) + N_GROUPS * H_DIM, H_DIM);
  norm(2);

  agg();
  k_gemm_mfma<4, true, 0, true><<<nblk_main, 256, 0, stream>>>(
      aggs, hsA, w4lb, w4rb, bb[3], praw, nullptr, batch,
      stat_ptr(3), stat_ptr(3) + N_GROUPS * H_DIM, H_DIM);
  norm(3);

  // layer 5 via linearity: P = h @ [W5l|W5r]^T (J=256), then
  // out = inv_deg * segsum(Pl[src]) + Pr + b5
  k_gemm_mfma<2, false, 1, true><<<nblk_l5, 256, 0, stream>>>(
      hsA, nullptr, w5cat, nullptr, nullptr, Plb, Prf, nullptr, nullptr, nullptr, H_DIM);
  k_agg_final<<<(N_NODES + 7) / 8, 256, 0, stream>>>(
      Plb, Prf, csr_off, csr_src, inv_deg, bb[4], (float*)d_out);
}